// Round 6
// baseline (304.861 us; speedup 1.0000x reference)
//
#include <hip/hip_runtime.h>
#include <stdint.h>

// MLA bf16-MFMA pipeline R11:
// B=2, N=2048, D=1024, L=512, H=16, Dh=64.
// Flash v5: QBLK=64 (4 waves x 16 q rows, no qb loop), KVBLK=128,
// grid 1024 blocks w/ bijective XCD swizzle (each XCD owns 4 bh -> K/V L2
// co-location). LDS 48KB -> 3 blocks/CU (launch_bounds(256,3)), 12 waves/CU.
// P swizzle fx(row) = ((row&7)<<4)^((row&8)<<2): restores row bit3 so the
// 4 quads' P-write bank groups are disjoint (R6/R10's 5.24M conflicts were
// ALL from 4-way P scalar writes; reads stay uniform 8 lanes/slot).
// Softmax log2-domain, defer-max THR=8, lane-partial l.
// GEMM templated on BN; BN=64 for k1v1 and out GEMMs (512 blocks, 2/CU).

typedef __attribute__((ext_vector_type(8))) __bf16 bf16x8;
typedef __attribute__((ext_vector_type(4))) float f32x4;

__device__ inline unsigned short f2bfu(float f) {
    __bf16 b = (__bf16)f;
    return __builtin_bit_cast(unsigned short, b);
}

__device__ inline float exp2_fast(float f) {
    return __builtin_amdgcn_exp2f(f);   // raw v_exp_f32
}

__device__ inline void load_lds16(const void* g, void* l) {
    __builtin_amdgcn_global_load_lds(
        (const __attribute__((address_space(1))) uint32_t*)g,
        (__attribute__((address_space(3))) uint32_t*)l, 16, 0, 0);
}

__device__ inline f32x4 mfma_bf16(bf16x8 a, bf16x8 b, f32x4 c) {
    return __builtin_amdgcn_mfma_f32_16x16x32_bf16(a, b, c, 0, 0, 0);
}

// ---------------- prep kernels ----------------

__global__ __launch_bounds__(256) void cvt_x_kernel(
    const float* __restrict__ src, unsigned short* __restrict__ dst)
{
    int i = (blockIdx.x * 256 + threadIdx.x) * 4;
    float4 v = *(const float4*)&src[i];
    ushort4 o;
    o.x = f2bfu(v.x); o.y = f2bfu(v.y); o.z = f2bfu(v.z); o.w = f2bfu(v.w);
    *(ushort4*)&dst[i] = o;
}

// z-batched: src f32 [R][C] -> dst bf16 [C][R] * scale. grid (C/64, R/64, nz)
__global__ __launch_bounds__(256) void transpose_w2_kernel(
    const float* __restrict__ s0, const float* __restrict__ s1,
    unsigned short* __restrict__ d0, unsigned short* __restrict__ d1,
    int R, int C, float sc0, float sc1)
{
    const float* src = blockIdx.z ? s1 : s0;
    unsigned short* dst = blockIdx.z ? d1 : d0;
    float sc = blockIdx.z ? sc1 : sc0;
    __shared__ float tile[64][65];
    int c0 = blockIdx.x * 64, r0 = blockIdx.y * 64;
    int t = threadIdx.x;
    int col = t & 63, rr = t >> 6;
#pragma unroll
    for (int i = 0; i < 16; ++i)
        tile[rr + i * 4][col] = src[(size_t)(r0 + rr + i * 4) * C + c0 + col];
    __syncthreads();
#pragma unroll
    for (int i = 0; i < 16; ++i) {
        int r2 = rr + i * 4;
        dst[(size_t)(c0 + r2) * R + r0 + col] = f2bfu(tile[col][r2] * sc);
    }
}

// v[b][n][h*64+d] (ld ldv) bf16 -> vt[(b*16+h)*64+d][n]. grid (2048/64, 32)
__global__ __launch_bounds__(256) void transpose_v_kernel(
    const unsigned short* __restrict__ v, int ldv, unsigned short* __restrict__ vt)
{
    __shared__ unsigned short tile[64][65];
    int n0 = blockIdx.x * 64, bh = blockIdx.y;
    int b = bh >> 4, h = bh & 15;
    int t = threadIdx.x;
    int r = t >> 3, c = t & 7;
#pragma unroll
    for (int p = 0; p < 2; ++p) {
        int row = r + p * 32;
        const unsigned short* src = v + (size_t)(b * 2048 + n0 + row) * ldv + h * 64 + c * 8;
        ushort4 a = *(const ushort4*)src;
        ushort4 b4 = *(const ushort4*)(src + 4);
        tile[row][c * 8 + 0] = a.x;  tile[row][c * 8 + 1] = a.y;
        tile[row][c * 8 + 2] = a.z;  tile[row][c * 8 + 3] = a.w;
        tile[row][c * 8 + 4] = b4.x; tile[row][c * 8 + 5] = b4.y;
        tile[row][c * 8 + 6] = b4.z; tile[row][c * 8 + 7] = b4.w;
    }
    __syncthreads();
#pragma unroll
    for (int p = 0; p < 2; ++p) {
        int d = r + p * 32;
        ushort4 o0, o1;
        o0.x = tile[c * 8 + 0][d]; o0.y = tile[c * 8 + 1][d];
        o0.z = tile[c * 8 + 2][d]; o0.w = tile[c * 8 + 3][d];
        o1.x = tile[c * 8 + 4][d]; o1.y = tile[c * 8 + 5][d];
        o1.z = tile[c * 8 + 6][d]; o1.w = tile[c * 8 + 7][d];
        unsigned short* dp = vt + (size_t)(bh * 64 + d) * 2048 + n0 + c * 8;
        *(ushort4*)dp = o0;
        *(ushort4*)(dp + 4) = o1;
    }
}

// ---------------- bf16 MFMA GEMM (m97 structure, z-batched, BN templated) ----
// C[M][N] = A[M][K] @ Bt[N][K]^T (+bias)(relu). 128xBN tile, BK=32.
// grid (N/BN, M/128, nz), block 256.
template<int BN>
__global__ __launch_bounds__(256) void gemm_bf16_kernel(
    const unsigned short* __restrict__ A0, const unsigned short* __restrict__ A1,
    const unsigned short* __restrict__ B0, const unsigned short* __restrict__ B1,
    void* __restrict__ C0, void* __restrict__ C1,
    int lda, int ldb, int ldc, int K,
    const float* __restrict__ bias, int relu, int out_f32)
{
    const unsigned short* A = blockIdx.z ? A1 : A0;
    const unsigned short* Bt = blockIdx.z ? B1 : B0;
    void* C = blockIdx.z ? C1 : C0;

    constexpr int NI = BN / 32;   // N-frags per wave
    __shared__ unsigned short Als[128 * 32];
    __shared__ unsigned short Bls[BN * 32];
    int t = threadIdx.x;
    int lane = t & 63, w = t >> 6;
    int n0 = blockIdx.x * BN, m0 = blockIdx.y * 128;
    int wm = (w & 1) * 64, wn = (w >> 1) * (BN / 2);
    int lrow = lane & 15, quad = lane >> 4;

    f32x4 acc[4][NI];
    f32x4 z = {0.f, 0.f, 0.f, 0.f};
#pragma unroll
    for (int i = 0; i < 4; ++i)
#pragma unroll
        for (int j = 0; j < NI; ++j) acc[i][j] = z;

    int c0 = t, c1 = t + 256;
    const unsigned short* ag0 = A + (size_t)(m0 + (c0 >> 2)) * lda + (c0 & 3) * 8;
    const unsigned short* ag1 = A + (size_t)(m0 + (c1 >> 2)) * lda + (c1 & 3) * 8;
    const unsigned short* bg0 = Bt + (size_t)(n0 + (c0 >> 2)) * ldb + (c0 & 3) * 8;
    const unsigned short* bg1 = Bt + (size_t)(n0 + ((c1 >> 2) & (BN - 1))) * ldb + (c1 & 3) * 8;

    for (int k0 = 0; k0 < K; k0 += 32) {
        __syncthreads();
        load_lds16(ag0 + k0, &Als[c0 * 8]);
        load_lds16(ag1 + k0, &Als[c1 * 8]);
        load_lds16(bg0 + k0, &Bls[c0 * 8]);
        if constexpr (BN == 128) load_lds16(bg1 + k0, &Bls[c1 * 8]);
        __syncthreads();

        bf16x8 af[4], bfr[NI];
#pragma unroll
        for (int mi = 0; mi < 4; ++mi)
            af[mi] = *(const bf16x8*)&Als[(wm + mi * 16 + lrow) * 32 + quad * 8];
#pragma unroll
        for (int ni = 0; ni < NI; ++ni)
            bfr[ni] = *(const bf16x8*)&Bls[(wn + ni * 16 + lrow) * 32 + quad * 8];
#pragma unroll
        for (int mi = 0; mi < 4; ++mi)
#pragma unroll
            for (int ni = 0; ni < NI; ++ni)
                acc[mi][ni] = mfma_bf16(af[mi], bfr[ni], acc[mi][ni]);
    }

#pragma unroll
    for (int mi = 0; mi < 4; ++mi)
#pragma unroll
        for (int ni = 0; ni < NI; ++ni)
#pragma unroll
            for (int r = 0; r < 4; ++r) {
                int row = m0 + wm + mi * 16 + quad * 4 + r;
                int col = n0 + wn + ni * 16 + lrow;
                float v = acc[mi][ni][r];
                if (bias) v += bias[col];
                if (relu) v = fmaxf(v, 0.0f);
                if (out_f32) ((float*)C)[(size_t)row * ldc + col] = v;
                else ((unsigned short*)C)[(size_t)row * ldc + col] = f2bfu(v);
            }
}

// ---------------- MFMA flash attention v5 ----------------
// Q (ldq, scaled by 0.125*log2e), K (ldk): head-interleaved; Vt [32*64][2048].
// grid 1024 1D blocks (XCD-swizzled), block 256 (4 waves). QBLK=64: wave w
// owns Q rows q0+w*16..+15. KVBLK=128, single-buffered, 2 barriers/tile.
// Softmax log2-domain, defer-max THR=8, lane-partial l. P per-wave [16][128]
// with swizzle fx(row)=((row&7)<<4)^((row&8)<<2): conflict-free b128 reads
// AND conflict-free scalar writes (quads land in disjoint bank groups).
__global__ __launch_bounds__(256, 3) void flash_mfma_kernel(
    const unsigned short* __restrict__ Q, int ldq,
    const unsigned short* __restrict__ K, int ldk,
    const unsigned short* __restrict__ Vt, unsigned short* __restrict__ O)
{
    __shared__ __align__(16) unsigned short Kls[2 * 128 * 32];  // [half d][kv row][32 d] 16KB
    __shared__ __align__(16) unsigned short Vls[4 * 64 * 32];   // [kv chunk][d row][32 kv] 16KB
    __shared__ __align__(16) unsigned short Pls[4][16 * 128];   // [wave][16 q][128 kv] swz 16KB

    // XCD swizzle: consecutive hardware blocks round-robin XCDs; remap so
    // XCD c gets logical blocks [c*128, (c+1)*128) = 4 consecutive bh.
    int pbid = blockIdx.x;
    int lbid = (pbid >> 3) + (pbid & 7) * 128;
    int q0 = (lbid & 31) * 64, bh = lbid >> 5;
    int b = bh >> 4, h = bh & 15;
    int t = threadIdx.x;
    int lane = t & 63, w = t >> 6;
    int lrow = lane & 15, quad = lane >> 4;

    // Q fragments (A-layout: row=lrow, k=quad*8)
    const unsigned short* qrow =
        Q + (size_t)(b * 2048 + q0 + w * 16 + lrow) * ldq + h * 64;
    bf16x8 qf0 = *(const bf16x8*)&qrow[quad * 8];
    bf16x8 qf1 = *(const bf16x8*)&qrow[32 + quad * 8];

    f32x4 z = {0.f, 0.f, 0.f, 0.f};
    f32x4 acco[4];
    float m_run[4], l_run[4];
#pragma unroll
    for (int r = 0; r < 4; ++r) {
        acco[r] = z;
        m_run[r] = -1e30f;
        l_run[r] = 0.f;   // lane-partial sum
    }

    // staging: thread t covers row t>>2 (0..63), segment (t&3)*8
    int row4 = t >> 2;
    int seg = (t & 3) * 8;
    const unsigned short* kg = K + (size_t)(b * 2048 + row4) * ldk + h * 64 + seg;
    const unsigned short* vg = Vt + (size_t)(bh * 64 + row4) * 2048 + seg;

    char* pb = (char*)&Pls[w][0];

    for (int kt = 0; kt < 2048; kt += 128) {
        __syncthreads();
        const unsigned short* kgk = kg + (size_t)kt * ldk;
        load_lds16(kgk,                 &Kls[t * 8]);
        load_lds16(kgk + 64 * ldk,      &Kls[t * 8 + 2048]);
        load_lds16(kgk + 32,            &Kls[4096 + t * 8]);
        load_lds16(kgk + 64 * ldk + 32, &Kls[4096 + t * 8 + 2048]);
        const unsigned short* vgk = vg + kt;
#pragma unroll
        for (int i = 0; i < 4; ++i)
            load_lds16(vgk + i * 32, &Vls[i * 2048 + t * 8]);
        __syncthreads();

        // S = Q K^T : 16 q rows x 128 kv
        f32x4 s[8];
        __builtin_amdgcn_s_setprio(1);
#pragma unroll
        for (int kt8 = 0; kt8 < 8; ++kt8) {
            bf16x8 k0 = *(const bf16x8*)&Kls[(kt8 * 16 + lrow) * 32 + quad * 8];
            bf16x8 k1 = *(const bf16x8*)&Kls[4096 + (kt8 * 16 + lrow) * 32 + quad * 8];
            s[kt8] = mfma_bf16(qf0, k0, z);
            s[kt8] = mfma_bf16(qf1, k1, s[kt8]);
        }
        __builtin_amdgcn_s_setprio(0);

        // softmax (log2 domain, defer-max THR=8)
        float pm[4];
#pragma unroll
        for (int r = 0; r < 4; ++r) {
            float a0 = fmaxf(fmaxf(s[0][r], s[1][r]), fmaxf(s[2][r], s[3][r]));
            float a1 = fmaxf(fmaxf(s[4][r], s[5][r]), fmaxf(s[6][r], s[7][r]));
            pm[r] = fmaxf(a0, a1);
        }
        bool ok = (pm[0] <= m_run[0] + 8.f) && (pm[1] <= m_run[1] + 8.f)
               && (pm[2] <= m_run[2] + 8.f) && (pm[3] <= m_run[3] + 8.f);
        if (!__all(ok)) {
            // rare path: full 16-lane max reduce + rescale
#pragma unroll
            for (int r = 0; r < 4; ++r) {
#pragma unroll
                for (int off = 1; off < 16; off <<= 1)
                    pm[r] = fmaxf(pm[r], __shfl_xor(pm[r], off, 64));
                float mnew = fmaxf(m_run[r], pm[r]);
                float al = exp2_fast(m_run[r] - mnew);
                m_run[r] = mnew;
                l_run[r] *= al;
#pragma unroll
                for (int nt = 0; nt < 4; ++nt) acco[nt][r] *= al;
            }
        }
        // p = exp2(s - m), lane-partial l, P -> swizzled LDS (wave-local)
#pragma unroll
        for (int kt8 = 0; kt8 < 8; ++kt8)
#pragma unroll
            for (int r = 0; r < 4; ++r) {
                float p = exp2_fast(s[kt8][r] - m_run[r]);
                l_run[r] += p;
                int row = quad * 4 + r;
                int boff = (row * 256 + (kt8 * 16 + lrow) * 2)
                         ^ ((row & 7) << 4) ^ ((row & 8) << 2);
                *(unsigned short*)(pb + boff) = f2bfu(p);
            }

        // PV: swizzled b128 P reads, V B-frags
        __builtin_amdgcn_s_setprio(1);
#pragma unroll
        for (int ks = 0; ks < 4; ++ks) {
            int rb = (lrow * 256 + ks * 64 + quad * 16)
                   ^ ((lrow & 7) << 4) ^ ((lrow & 8) << 2);
            bf16x8 pf = *(const bf16x8*)(pb + rb);
#pragma unroll
            for (int nt = 0; nt < 4; ++nt) {
                bf16x8 vf = *(const bf16x8*)&Vls[ks * 2048 + (nt * 16 + lrow) * 32 + quad * 8];
                acco[nt] = mfma_bf16(pf, vf, acco[nt]);
            }
        }
        __builtin_amdgcn_s_setprio(0);
    }

    // epilogue: reduce lane-partial l across the 16-lane row group, write O
#pragma unroll
    for (int r = 0; r < 4; ++r) {
        float lr = l_run[r];
#pragma unroll
        for (int off = 1; off < 16; off <<= 1)
            lr += __shfl_xor(lr, off, 64);
        float rl = 1.0f / lr;
        int row = b * 2048 + q0 + w * 16 + quad * 4 + r;
#pragma unroll
        for (int nt = 0; nt < 4; ++nt)
            O[(size_t)row * 1024 + h * 64 + nt * 16 + lrow] =
                f2bfu(acco[nt][r] * rl);
    }
}

// ---------------- launch ----------------

extern "C" void kernel_launch(void* const* d_in, const int* in_sizes, int n_in,
                              void* d_out, int out_size, void* d_ws, size_t ws_size,
                              hipStream_t stream) {
    const float* x   = (const float*)d_in[0];
    const float* Wq  = (const float*)d_in[1];
    const float* Wkv = (const float*)d_in[2];
    const float* Wk1 = (const float*)d_in[3];
    const float* Wk2 = (const float*)d_in[4];
    const float* Wv1 = (const float*)d_in[5];
    const float* Wv2 = (const float*)d_in[6];
    const float* Wo  = (const float*)d_in[7];
    const float* bo  = (const float*)d_in[8];
    float* out = (float*)d_out;

    unsigned short* p = (unsigned short*)d_ws;
    unsigned short* xb    = p; p += 4194304;   // [4096][1024]
    unsigned short* WqkvT = p; p += 3145728;   // [3072][1024]  (Wq^T scaled | Wkv^T)
    unsigned short* WoT   = p; p += 1048576;   // [1024][1024]
    unsigned short* Wk1T  = p; p += 524288;    // [512][1024]
    unsigned short* Wv1T  = p; p += 524288;    // [512][1024]
    unsigned short* Wk2T  = p; p += 524288;    // [1024][512]
    unsigned short* Wv2T  = p; p += 524288;    // [1024][512]
    unsigned short* qkv   = p; p += 12582912;  // [4096][3072]  (q | k-in | v-in)
    unsigned short* tmpb  = p; p += 4194304;   // [4096][1024]  (k1 | v1), reused as attn
    unsigned short* kvo   = p; p += 8388608;   // [4096][2048]  (k | v)
    unsigned short* vtb   = p; p += 4194304;   // [32*64][2048]
    unsigned short* attnb = tmpb;              // alias: tmp dead after k2v2

    dim3 blk(256);
    const float qscale = 0.125f * 1.44269504f;  // Dh^-0.5 * log2(e)

    cvt_x_kernel<<<4096, blk, 0, stream>>>(x, xb);
    transpose_w2_kernel<<<dim3(16, 16, 2), blk, 0, stream>>>(Wq, Wo, WqkvT, WoT, 1024, 1024, qscale, 1.0f);
    transpose_w2_kernel<<<dim3(32, 16, 1), blk, 0, stream>>>(Wkv, Wkv, WqkvT + 1048576, WqkvT + 1048576, 1024, 2048, 1.0f, 1.0f);
    transpose_w2_kernel<<<dim3(8, 16, 2),  blk, 0, stream>>>(Wk1, Wv1, Wk1T, Wv1T, 1024, 512, 1.0f, 1.0f);
    transpose_w2_kernel<<<dim3(16, 8, 2),  blk, 0, stream>>>(Wk2, Wv2, Wk2T, Wv2T, 512, 1024, 1.0f, 1.0f);

    // qkv = x @ [Wq*s | Wkv]   -> qkv [4096][3072]
    gemm_bf16_kernel<128><<<dim3(24, 32, 1), blk, 0, stream>>>(
        xb, xb, WqkvT, WqkvT, qkv, qkv, 1024, 1024, 3072, 1024, nullptr, 0, 0);
    // k1 = relu(kv_k @ Wk1), v1 = relu(kv_v @ Wv1)  -> tmpb [4096][512|512]
    // BN=64: 512 blocks (2/CU) instead of 256 (1/CU)
    gemm_bf16_kernel<64><<<dim3(8, 32, 2), blk, 0, stream>>>(
        qkv + 1024, qkv + 2048, Wk1T, Wv1T, tmpb, tmpb + 512,
        3072, 1024, 1024, 1024, nullptr, 1, 0);
    // k = k1 @ Wk2, v = v1 @ Wv2  -> kvo [4096][1024|1024]   (ldb = 512!)
    gemm_bf16_kernel<128><<<dim3(8, 32, 2), blk, 0, stream>>>(
        tmpb, tmpb + 512, Wk2T, Wv2T, kvo, kvo + 1024,
        1024, 512, 2048, 512, nullptr, 0, 0);

    transpose_v_kernel<<<dim3(32, 32), blk, 0, stream>>>(kvo + 1024, 2048, vtb);
    flash_mfma_kernel<<<dim3(1024), blk, 0, stream>>>(qkv, 3072, kvo, 2048, vtb, attnb);
    // out = attn @ Wo + bo (fp32), BN=64 for occupancy
    gemm_bf16_kernel<64><<<dim3(16, 32, 1), blk, 0, stream>>>(
        attnb, attnb, WoT, WoT, out, out, 1024, 1024, 1024, 1024, bo, 0, 1);
}

// Round 7
// 290.124 us; speedup vs baseline: 1.0508x; 1.0508x over previous
//
#include <hip/hip_runtime.h>
#include <stdint.h>

// MLA bf16-MFMA pipeline R12:
// B=2, N=2048, D=1024, L=512, H=16, Dh=64.
// Flash v6 = R10 per-work structure (QBLK=128: 4 waves x 32 q rows as 2
// q-subtiles; V-frags shared across qb; defer-max THR=8; lane-partial l;
// P [16][64] XOR-swizzled (row&7)<<4) with:
//  - KVBLK 128->64: same LDS/MFMA/VALU cost per unit work, half tile LDS
//  - K/V double-buffered (48KB total): stage(t+1) issued BEFORE compute(t),
//    ONE barrier per tile -> the vmcnt(0) barrier drain lands after ~1.7K
//    cycles of compute instead of exposing load latency per tile (T3-min)
//  - XCD-swizzled 1D grid 512 = 8 XCDs x 64 blocks (R11-proven: FETCH 5.7x
//    lower; each XCD owns 4 bh -> K/V L2-resident)
// MODEL NOTE: SQ_LDS_BANK_CONFLICT = 4 x ds_read_b128 count on this kernel
// family (verified bit-exact across R5/R6/R7/R10/R11) — it is the b128
// wide-read tax (m134), not a fixable bank conflict. Don't chase it.
// GEMM templated on BN; BN=64 for k1v1 and out GEMMs (512 blocks, 2/CU).

typedef __attribute__((ext_vector_type(8))) __bf16 bf16x8;
typedef __attribute__((ext_vector_type(4))) float f32x4;

__device__ inline unsigned short f2bfu(float f) {
    __bf16 b = (__bf16)f;
    return __builtin_bit_cast(unsigned short, b);
}

__device__ inline float exp2_fast(float f) {
    return __builtin_amdgcn_exp2f(f);   // raw v_exp_f32
}

__device__ inline void load_lds16(const void* g, void* l) {
    __builtin_amdgcn_global_load_lds(
        (const __attribute__((address_space(1))) uint32_t*)g,
        (__attribute__((address_space(3))) uint32_t*)l, 16, 0, 0);
}

__device__ inline f32x4 mfma_bf16(bf16x8 a, bf16x8 b, f32x4 c) {
    return __builtin_amdgcn_mfma_f32_16x16x32_bf16(a, b, c, 0, 0, 0);
}

// ---------------- prep kernels ----------------

__global__ __launch_bounds__(256) void cvt_x_kernel(
    const float* __restrict__ src, unsigned short* __restrict__ dst)
{
    int i = (blockIdx.x * 256 + threadIdx.x) * 4;
    float4 v = *(const float4*)&src[i];
    ushort4 o;
    o.x = f2bfu(v.x); o.y = f2bfu(v.y); o.z = f2bfu(v.z); o.w = f2bfu(v.w);
    *(ushort4*)&dst[i] = o;
}

// z-batched: src f32 [R][C] -> dst bf16 [C][R] * scale. grid (C/64, R/64, nz)
__global__ __launch_bounds__(256) void transpose_w2_kernel(
    const float* __restrict__ s0, const float* __restrict__ s1,
    unsigned short* __restrict__ d0, unsigned short* __restrict__ d1,
    int R, int C, float sc0, float sc1)
{
    const float* src = blockIdx.z ? s1 : s0;
    unsigned short* dst = blockIdx.z ? d1 : d0;
    float sc = blockIdx.z ? sc1 : sc0;
    __shared__ float tile[64][65];
    int c0 = blockIdx.x * 64, r0 = blockIdx.y * 64;
    int t = threadIdx.x;
    int col = t & 63, rr = t >> 6;
#pragma unroll
    for (int i = 0; i < 16; ++i)
        tile[rr + i * 4][col] = src[(size_t)(r0 + rr + i * 4) * C + c0 + col];
    __syncthreads();
#pragma unroll
    for (int i = 0; i < 16; ++i) {
        int r2 = rr + i * 4;
        dst[(size_t)(c0 + r2) * R + r0 + col] = f2bfu(tile[col][r2] * sc);
    }
}

// v[b][n][h*64+d] (ld ldv) bf16 -> vt[(b*16+h)*64+d][n]. grid (2048/64, 32)
__global__ __launch_bounds__(256) void transpose_v_kernel(
    const unsigned short* __restrict__ v, int ldv, unsigned short* __restrict__ vt)
{
    __shared__ unsigned short tile[64][65];
    int n0 = blockIdx.x * 64, bh = blockIdx.y;
    int b = bh >> 4, h = bh & 15;
    int t = threadIdx.x;
    int r = t >> 3, c = t & 7;
#pragma unroll
    for (int p = 0; p < 2; ++p) {
        int row = r + p * 32;
        const unsigned short* src = v + (size_t)(b * 2048 + n0 + row) * ldv + h * 64 + c * 8;
        ushort4 a = *(const ushort4*)src;
        ushort4 b4 = *(const ushort4*)(src + 4);
        tile[row][c * 8 + 0] = a.x;  tile[row][c * 8 + 1] = a.y;
        tile[row][c * 8 + 2] = a.z;  tile[row][c * 8 + 3] = a.w;
        tile[row][c * 8 + 4] = b4.x; tile[row][c * 8 + 5] = b4.y;
        tile[row][c * 8 + 6] = b4.z; tile[row][c * 8 + 7] = b4.w;
    }
    __syncthreads();
#pragma unroll
    for (int p = 0; p < 2; ++p) {
        int d = r + p * 32;
        ushort4 o0, o1;
        o0.x = tile[c * 8 + 0][d]; o0.y = tile[c * 8 + 1][d];
        o0.z = tile[c * 8 + 2][d]; o0.w = tile[c * 8 + 3][d];
        o1.x = tile[c * 8 + 4][d]; o1.y = tile[c * 8 + 5][d];
        o1.z = tile[c * 8 + 6][d]; o1.w = tile[c * 8 + 7][d];
        unsigned short* dp = vt + (size_t)(bh * 64 + d) * 2048 + n0 + c * 8;
        *(ushort4*)dp = o0;
        *(ushort4*)(dp + 4) = o1;
    }
}

// ---------------- bf16 MFMA GEMM (m97 structure, z-batched, BN templated) ----
// C[M][N] = A[M][K] @ Bt[N][K]^T (+bias)(relu). 128xBN tile, BK=32.
// grid (N/BN, M/128, nz), block 256.
template<int BN>
__global__ __launch_bounds__(256) void gemm_bf16_kernel(
    const unsigned short* __restrict__ A0, const unsigned short* __restrict__ A1,
    const unsigned short* __restrict__ B0, const unsigned short* __restrict__ B1,
    void* __restrict__ C0, void* __restrict__ C1,
    int lda, int ldb, int ldc, int K,
    const float* __restrict__ bias, int relu, int out_f32)
{
    const unsigned short* A = blockIdx.z ? A1 : A0;
    const unsigned short* Bt = blockIdx.z ? B1 : B0;
    void* C = blockIdx.z ? C1 : C0;

    constexpr int NI = BN / 32;   // N-frags per wave
    __shared__ unsigned short Als[128 * 32];
    __shared__ unsigned short Bls[BN * 32];
    int t = threadIdx.x;
    int lane = t & 63, w = t >> 6;
    int n0 = blockIdx.x * BN, m0 = blockIdx.y * 128;
    int wm = (w & 1) * 64, wn = (w >> 1) * (BN / 2);
    int lrow = lane & 15, quad = lane >> 4;

    f32x4 acc[4][NI];
    f32x4 z = {0.f, 0.f, 0.f, 0.f};
#pragma unroll
    for (int i = 0; i < 4; ++i)
#pragma unroll
        for (int j = 0; j < NI; ++j) acc[i][j] = z;

    int c0 = t, c1 = t + 256;
    const unsigned short* ag0 = A + (size_t)(m0 + (c0 >> 2)) * lda + (c0 & 3) * 8;
    const unsigned short* ag1 = A + (size_t)(m0 + (c1 >> 2)) * lda + (c1 & 3) * 8;
    const unsigned short* bg0 = Bt + (size_t)(n0 + (c0 >> 2)) * ldb + (c0 & 3) * 8;
    const unsigned short* bg1 = Bt + (size_t)(n0 + ((c1 >> 2) & (BN - 1))) * ldb + (c1 & 3) * 8;

    for (int k0 = 0; k0 < K; k0 += 32) {
        __syncthreads();
        load_lds16(ag0 + k0, &Als[c0 * 8]);
        load_lds16(ag1 + k0, &Als[c1 * 8]);
        load_lds16(bg0 + k0, &Bls[c0 * 8]);
        if constexpr (BN == 128) load_lds16(bg1 + k0, &Bls[c1 * 8]);
        __syncthreads();

        bf16x8 af[4], bfr[NI];
#pragma unroll
        for (int mi = 0; mi < 4; ++mi)
            af[mi] = *(const bf16x8*)&Als[(wm + mi * 16 + lrow) * 32 + quad * 8];
#pragma unroll
        for (int ni = 0; ni < NI; ++ni)
            bfr[ni] = *(const bf16x8*)&Bls[(wn + ni * 16 + lrow) * 32 + quad * 8];
#pragma unroll
        for (int mi = 0; mi < 4; ++mi)
#pragma unroll
            for (int ni = 0; ni < NI; ++ni)
                acc[mi][ni] = mfma_bf16(af[mi], bfr[ni], acc[mi][ni]);
    }

#pragma unroll
    for (int mi = 0; mi < 4; ++mi)
#pragma unroll
        for (int ni = 0; ni < NI; ++ni)
#pragma unroll
            for (int r = 0; r < 4; ++r) {
                int row = m0 + wm + mi * 16 + quad * 4 + r;
                int col = n0 + wn + ni * 16 + lrow;
                float v = acc[mi][ni][r];
                if (bias) v += bias[col];
                if (relu) v = fmaxf(v, 0.0f);
                if (out_f32) ((float*)C)[(size_t)row * ldc + col] = v;
                else ((unsigned short*)C)[(size_t)row * ldc + col] = f2bfu(v);
            }
}

// ---------------- MFMA flash attention v6 ----------------
// Q (ldq, scaled by 0.125*log2e), K (ldk): head-interleaved; Vt [32*64][2048].
// grid 512 1D (XCD-swizzled), block 256 (4 waves). Wave w owns Q rows
// w*32..+31 as 2 q-subtiles of 16. KVBLK=64, K/V double-buffered;
// stage(t+1) issued before compute(t); ONE barrier per tile.
// Softmax log2-domain, defer-max THR=8, lane-partial l. P per-wave per-qb
// [16][64] hw, XOR swizzle byte^=(row&7)<<4 on write and read.
__global__ __launch_bounds__(256, 2) void flash_mfma_kernel(
    const unsigned short* __restrict__ Q, int ldq,
    const unsigned short* __restrict__ K, int ldk,
    const unsigned short* __restrict__ Vt, unsigned short* __restrict__ O)
{
    __shared__ __align__(16) unsigned short Kls[2][2 * 64 * 32]; // [buf][half d][64 kv][32 d] 8KB ea
    __shared__ __align__(16) unsigned short Vls[2][2 * 64 * 32]; // [buf][ks][64 d][32 kv]   8KB ea
    __shared__ __align__(16) unsigned short Pls[4][2][16 * 64];  // [wave][qb][16 q][64 kv] swz 16KB

    // XCD swizzle: 512 = 8 XCDs x 64; XCD c gets logical blocks [c*64,(c+1)*64)
    // = 4 consecutive bh (K/V working set 2MB < 4MB L2).
    int pbid = blockIdx.x;
    int lbid = (pbid >> 3) + (pbid & 7) * 64;
    int q0 = (lbid & 15) * 128, bh = lbid >> 4;
    int b = bh >> 4, h = bh & 15;
    int t = threadIdx.x;
    int lane = t & 63, w = t >> 6;
    int lrow = lane & 15, quad = lane >> 4;

    // Q fragments: 2 q-subtiles x 2 k-halves (A-layout: row=lrow, k=quad*8)
    bf16x8 qf[2][2];
#pragma unroll
    for (int qb = 0; qb < 2; ++qb) {
        const unsigned short* qrow =
            Q + (size_t)(b * 2048 + q0 + w * 32 + qb * 16 + lrow) * ldq + h * 64;
        qf[qb][0] = *(const bf16x8*)&qrow[quad * 8];
        qf[qb][1] = *(const bf16x8*)&qrow[32 + quad * 8];
    }

    f32x4 z = {0.f, 0.f, 0.f, 0.f};
    f32x4 acco[2][4];
    float m_run[2][4], l_run[2][4];
#pragma unroll
    for (int qb = 0; qb < 2; ++qb)
#pragma unroll
        for (int r = 0; r < 4; ++r) {
            acco[qb][r] = z;
            m_run[qb][r] = -1e30f;
            l_run[qb][r] = 0.f;   // lane-partial sum
        }

    // staging: thread t covers row t>>2 (0..63), segment (t&3)*8
    int row4 = t >> 2;
    int seg = (t & 3) * 8;
    const unsigned short* kg = K + (size_t)(b * 2048 + row4) * ldk + h * 64 + seg;
    const unsigned short* vg = Vt + (size_t)(bh * 64 + row4) * 2048 + seg;

    char* pb[2] = { (char*)&Pls[w][0][0], (char*)&Pls[w][1][0] };

    // prologue: stage tile 0 -> buf 0
    load_lds16(kg,      &Kls[0][t * 8]);
    load_lds16(kg + 32, &Kls[0][2048 + t * 8]);
    load_lds16(vg,      &Vls[0][t * 8]);
    load_lds16(vg + 32, &Vls[0][2048 + t * 8]);
    __syncthreads();

    int cur = 0;
    for (int kt = 0; kt < 2048; kt += 64) {
        // issue next-tile stage into buf cur^1; latency hides under compute
        if (kt + 64 < 2048) {
            const unsigned short* kgk = kg + (size_t)(kt + 64) * ldk;
            const unsigned short* vgk = vg + kt + 64;
            int nb = cur ^ 1;
            load_lds16(kgk,      &Kls[nb][t * 8]);
            load_lds16(kgk + 32, &Kls[nb][2048 + t * 8]);
            load_lds16(vgk,      &Vls[nb][t * 8]);
            load_lds16(vgk + 32, &Vls[nb][2048 + t * 8]);
        }

        // S = Q K^T : 32 q rows x 64 kv; K-frags shared across q-subtiles
        f32x4 s[2][4];
        __builtin_amdgcn_s_setprio(1);
#pragma unroll
        for (int kt8 = 0; kt8 < 4; ++kt8) {
            bf16x8 k0 = *(const bf16x8*)&Kls[cur][(kt8 * 16 + lrow) * 32 + quad * 8];
            bf16x8 k1 = *(const bf16x8*)&Kls[cur][2048 + (kt8 * 16 + lrow) * 32 + quad * 8];
            s[0][kt8] = mfma_bf16(qf[0][0], k0, z);
            s[0][kt8] = mfma_bf16(qf[0][1], k1, s[0][kt8]);
            s[1][kt8] = mfma_bf16(qf[1][0], k0, z);
            s[1][kt8] = mfma_bf16(qf[1][1], k1, s[1][kt8]);
        }
        __builtin_amdgcn_s_setprio(0);

        // per q-subtile: softmax (log2, defer-max) -> P (swizzled writes)
#pragma unroll
        for (int qb = 0; qb < 2; ++qb) {
            float pm[4];
#pragma unroll
            for (int r = 0; r < 4; ++r)
                pm[r] = fmaxf(fmaxf(s[qb][0][r], s[qb][1][r]),
                              fmaxf(s[qb][2][r], s[qb][3][r]));
            bool ok = (pm[0] <= m_run[qb][0] + 8.f) && (pm[1] <= m_run[qb][1] + 8.f)
                   && (pm[2] <= m_run[qb][2] + 8.f) && (pm[3] <= m_run[qb][3] + 8.f);
            if (!__all(ok)) {
                // rare path: full 16-lane max reduce + rescale
#pragma unroll
                for (int r = 0; r < 4; ++r) {
#pragma unroll
                    for (int off = 1; off < 16; off <<= 1)
                        pm[r] = fmaxf(pm[r], __shfl_xor(pm[r], off, 64));
                    float mnew = fmaxf(m_run[qb][r], pm[r]);
                    float al = exp2_fast(m_run[qb][r] - mnew);
                    m_run[qb][r] = mnew;
                    l_run[qb][r] *= al;
#pragma unroll
                    for (int nt = 0; nt < 4; ++nt) acco[qb][nt][r] *= al;
                }
            }
            // p = exp2(s - m), lane-partial l, P -> swizzled LDS (wave-local)
#pragma unroll
            for (int kt8 = 0; kt8 < 4; ++kt8)
#pragma unroll
                for (int r = 0; r < 4; ++r) {
                    float p = exp2_fast(s[qb][kt8][r] - m_run[qb][r]);
                    l_run[qb][r] += p;
                    int row = quad * 4 + r;
                    int boff = (row * 128 + (kt8 * 16 + lrow) * 2) ^ ((row & 7) << 4);
                    *(unsigned short*)(pb[qb] + boff) = f2bfu(p);
                }
        }

        // PV: V-frags shared across both q-subtiles; swizzled b128 P reads
        __builtin_amdgcn_s_setprio(1);
#pragma unroll
        for (int ks = 0; ks < 2; ++ks) {
            int rb = (lrow * 128 + ks * 64 + quad * 16) ^ ((lrow & 7) << 4);
            bf16x8 pf0 = *(const bf16x8*)(pb[0] + rb);
            bf16x8 pf1 = *(const bf16x8*)(pb[1] + rb);
#pragma unroll
            for (int nt = 0; nt < 4; ++nt) {
                bf16x8 vf = *(const bf16x8*)&Vls[cur][ks * 2048 + (nt * 16 + lrow) * 32 + quad * 8];
                acco[0][nt] = mfma_bf16(pf0, vf, acco[0][nt]);
                acco[1][nt] = mfma_bf16(pf1, vf, acco[1][nt]);
            }
        }
        __builtin_amdgcn_s_setprio(0);

        __syncthreads();   // drains vmcnt(0): next tile staged; buf[cur] free
        cur ^= 1;
    }

    // epilogue: reduce lane-partial l across the 16-lane row group, write O
#pragma unroll
    for (int qb = 0; qb < 2; ++qb)
#pragma unroll
        for (int r = 0; r < 4; ++r) {
            float lr = l_run[qb][r];
#pragma unroll
            for (int off = 1; off < 16; off <<= 1)
                lr += __shfl_xor(lr, off, 64);
            float rl = 1.0f / lr;
            int row = b * 2048 + q0 + w * 32 + qb * 16 + quad * 4 + r;
#pragma unroll
            for (int nt = 0; nt < 4; ++nt)
                O[(size_t)row * 1024 + h * 64 + nt * 16 + lrow] =
                    f2bfu(acco[qb][nt][r] * rl);
        }
}

// ---------------- launch ----------------

extern "C" void kernel_launch(void* const* d_in, const int* in_sizes, int n_in,
                              void* d_out, int out_size, void* d_ws, size_t ws_size,
                              hipStream_t stream) {
    const float* x   = (const float*)d_in[0];
    const float* Wq  = (const float*)d_in[1];
    const float* Wkv = (const float*)d_in[2];
    const float* Wk1 = (const float*)d_in[3];
    const float* Wk2 = (const float*)d_in[4];
    const float* Wv1 = (const float*)d_in[5];
    const float* Wv2 = (const float*)d_in[6];
    const float* Wo  = (const float*)d_in[7];
    const float* bo  = (const float*)d_in[8];
    float* out = (float*)d_out;

    unsigned short* p = (unsigned short*)d_ws;
    unsigned short* xb    = p; p += 4194304;   // [4096][1024]
    unsigned short* WqkvT = p; p += 3145728;   // [3072][1024]  (Wq^T scaled | Wkv^T)
    unsigned short* WoT   = p; p += 1048576;   // [1024][1024]
    unsigned short* Wk1T  = p; p += 524288;    // [512][1024]
    unsigned short* Wv1T  = p; p += 524288;    // [512][1024]
    unsigned short* Wk2T  = p; p += 524288;    // [1024][512]
    unsigned short* Wv2T  = p; p += 524288;    // [1024][512]
    unsigned short* qkv   = p; p += 12582912;  // [4096][3072]  (q | k-in | v-in)
    unsigned short* tmpb  = p; p += 4194304;   // [4096][1024]  (k1 | v1), reused as attn
    unsigned short* kvo   = p; p += 8388608;   // [4096][2048]  (k | v)
    unsigned short* vtb   = p; p += 4194304;   // [32*64][2048]
    unsigned short* attnb = tmpb;              // alias: tmp dead after k2v2

    dim3 blk(256);
    const float qscale = 0.125f * 1.44269504f;  // Dh^-0.5 * log2(e)

    cvt_x_kernel<<<4096, blk, 0, stream>>>(x, xb);
    transpose_w2_kernel<<<dim3(16, 16, 2), blk, 0, stream>>>(Wq, Wo, WqkvT, WoT, 1024, 1024, qscale, 1.0f);
    transpose_w2_kernel<<<dim3(32, 16, 1), blk, 0, stream>>>(Wkv, Wkv, WqkvT + 1048576, WqkvT + 1048576, 1024, 2048, 1.0f, 1.0f);
    transpose_w2_kernel<<<dim3(8, 16, 2),  blk, 0, stream>>>(Wk1, Wv1, Wk1T, Wv1T, 1024, 512, 1.0f, 1.0f);
    transpose_w2_kernel<<<dim3(16, 8, 2),  blk, 0, stream>>>(Wk2, Wv2, Wk2T, Wv2T, 512, 1024, 1.0f, 1.0f);

    // qkv = x @ [Wq*s | Wkv]   -> qkv [4096][3072]
    gemm_bf16_kernel<128><<<dim3(24, 32, 1), blk, 0, stream>>>(
        xb, xb, WqkvT, WqkvT, qkv, qkv, 1024, 1024, 3072, 1024, nullptr, 0, 0);
    // k1 = relu(kv_k @ Wk1), v1 = relu(kv_v @ Wv1)  -> tmpb [4096][512|512]
    gemm_bf16_kernel<64><<<dim3(8, 32, 2), blk, 0, stream>>>(
        qkv + 1024, qkv + 2048, Wk1T, Wv1T, tmpb, tmpb + 512,
        3072, 1024, 1024, 1024, nullptr, 1, 0);
    // k = k1 @ Wk2, v = v1 @ Wv2  -> kvo [4096][1024|1024]   (ldb = 512!)
    gemm_bf16_kernel<128><<<dim3(8, 32, 2), blk, 0, stream>>>(
        tmpb, tmpb + 512, Wk2T, Wv2T, kvo, kvo + 1024,
        1024, 512, 2048, 512, nullptr, 0, 0);

    transpose_v_kernel<<<dim3(32, 32), blk, 0, stream>>>(kvo + 1024, 2048, vtb);
    flash_mfma_kernel<<<dim3(512), blk, 0, stream>>>(qkv, 3072, kvo, 2048, vtb, attnb);
    // out = attn @ Wo + bo (fp32), BN=64 for occupancy
    gemm_bf16_kernel<64><<<dim3(16, 32, 1), blk, 0, stream>>>(
        attnb, attnb, WoT, WoT, out, out, 1024, 1024, 1024, 1024, bo, 0, 1);
}

// Round 8
// 281.274 us; speedup vs baseline: 1.0839x; 1.0315x over previous
//
#include <hip/hip_runtime.h>
#include <stdint.h>

// MLA bf16-MFMA pipeline R13:
// B=2, N=2048, D=1024, L=512, H=16, Dh=64.
// Launch-graph compaction: 11 -> 6 kernels.
//  - prep_kernel: cvt_x + all 4 weight transposes in ONE launch (5632 blocks,
//    dispatch on blockIdx.x; whole blocks take one path, no divergence).
//  - transpose_v DELETED: k2v2's v-half (z=1) writes its C tile directly
//    transposed into vtb (b64-packed stores, 4 consecutive n per lane).
//    k-half writes kvo with ldc=1024; flash ldk=1024.
// Flash v6 unchanged from R12 (72 µs): QBLK=128, KVBLK=64 dbuf, XCD swizzle,
// defer-max, lane-partial l, P XOR-swizzle.
// MODEL NOTES (verified this session):
//  - SQ_LDS_BANK_CONFLICT = 4 x ds_read_b128 count (b128 wide-read tax, m134);
//    bit-exact across R5/R6/R7/R10/R11/R12. Not a fixable conflict.
//  - Flash is NOT latency-bound (dbuf null twice: R7, R12), NOT HBM-bound
//    (XCD swizzle cut FETCH 5.7x, time unchanged). ~5400 cyc/CU-tile floor
//    with LDS~60%/VALU~38%/MFMA~18% overlapped.
// GEMM templated on BN; BN=64 for k1v1 and out GEMMs (512 blocks, 2/CU).

typedef __attribute__((ext_vector_type(8))) __bf16 bf16x8;
typedef __attribute__((ext_vector_type(4))) float f32x4;

__device__ inline unsigned short f2bfu(float f) {
    __bf16 b = (__bf16)f;
    return __builtin_bit_cast(unsigned short, b);
}

__device__ inline float exp2_fast(float f) {
    return __builtin_amdgcn_exp2f(f);   // raw v_exp_f32
}

__device__ inline void load_lds16(const void* g, void* l) {
    __builtin_amdgcn_global_load_lds(
        (const __attribute__((address_space(1))) uint32_t*)g,
        (__attribute__((address_space(3))) uint32_t*)l, 16, 0, 0);
}

__device__ inline f32x4 mfma_bf16(bf16x8 a, bf16x8 b, f32x4 c) {
    return __builtin_amdgcn_mfma_f32_16x16x32_bf16(a, b, c, 0, 0, 0);
}

// ---------------- merged prep kernel ----------------
// blocks [0,4096): cvt x f32->bf16 (4 elems/thread)
// blocks [4096,5632): weight transposes, src f32 [R][C] -> dst bf16 [C][R]*sc
__global__ __launch_bounds__(256) void prep_kernel(
    const float* __restrict__ x, unsigned short* __restrict__ xb,
    const float* __restrict__ Wq,  const float* __restrict__ Wo,
    const float* __restrict__ Wkv,
    const float* __restrict__ Wk1, const float* __restrict__ Wv1,
    const float* __restrict__ Wk2, const float* __restrict__ Wv2,
    unsigned short* __restrict__ WqkvT, unsigned short* __restrict__ WoT,
    unsigned short* __restrict__ Wk1T,  unsigned short* __restrict__ Wv1T,
    unsigned short* __restrict__ Wk2T,  unsigned short* __restrict__ Wv2T,
    float qscale)
{
    __shared__ float tile[64][65];
    int id = blockIdx.x;
    int t = threadIdx.x;

    if (id < 4096) {   // ---- cvt_x ----
        int i = (id * 256 + t) * 4;
        float4 v = *(const float4*)&x[i];
        ushort4 o;
        o.x = f2bfu(v.x); o.y = f2bfu(v.y); o.z = f2bfu(v.z); o.w = f2bfu(v.w);
        *(ushort4*)&xb[i] = o;
        return;
    }

    // ---- transposes ----
    int r = id - 4096;
    const float* src; unsigned short* dst; int R, C; float sc; int bx, by;
    if (r < 512) {          // Wq / Wo : 16 x 16 x 2
        int z = r >> 8; int rr = r & 255; bx = rr & 15; by = rr >> 4;
        src = z ? Wo : Wq; dst = z ? WoT : WqkvT;
        R = 1024; C = 1024; sc = z ? 1.0f : qscale;
    } else if (r < 1024) {  // Wkv : 32 x 16
        int rr = r - 512; bx = rr & 31; by = rr >> 5;
        src = Wkv; dst = WqkvT + 1048576; R = 1024; C = 2048; sc = 1.0f;
    } else if (r < 1280) {  // Wk1 / Wv1 : 8 x 16 x 2
        int rr = r - 1024; int z = rr >> 7; rr &= 127; bx = rr & 7; by = rr >> 3;
        src = z ? Wv1 : Wk1; dst = z ? Wv1T : Wk1T;
        R = 1024; C = 512; sc = 1.0f;
    } else {                // Wk2 / Wv2 : 16 x 8 x 2
        int rr = r - 1280; int z = rr >> 7; rr &= 127; bx = rr & 15; by = rr >> 4;
        src = z ? Wv2 : Wk2; dst = z ? Wv2T : Wk2T;
        R = 512; C = 1024; sc = 1.0f;
    }

    int c0 = bx * 64, r0 = by * 64;
    int col = t & 63, rr4 = t >> 6;
#pragma unroll
    for (int i = 0; i < 16; ++i)
        tile[rr4 + i * 4][col] = src[(size_t)(r0 + rr4 + i * 4) * C + c0 + col];
    __syncthreads();
#pragma unroll
    for (int i = 0; i < 16; ++i) {
        int r2 = rr4 + i * 4;
        dst[(size_t)(c0 + r2) * R + r0 + col] = f2bfu(tile[col][r2] * sc);
    }
}

// ---------------- bf16 MFMA GEMM (m97 structure, z-batched, BN templated) ----
// C[M][N] = A[M][K] @ Bt[N][K]^T (+bias)(relu). 128xBN tile, BK=32.
// grid (N/BN, M/128, nz), block 256.
// OUTVT: on the z=1 path, write C transposed into C1 as
// vt[(b*1024 + col) * 2048 + (m & 2047)] (b = m >> 11), b64-packed over r.
template<int BN, bool OUTVT = false>
__global__ __launch_bounds__(256) void gemm_bf16_kernel(
    const unsigned short* __restrict__ A0, const unsigned short* __restrict__ A1,
    const unsigned short* __restrict__ B0, const unsigned short* __restrict__ B1,
    void* __restrict__ C0, void* __restrict__ C1,
    int lda, int ldb, int ldc, int K,
    const float* __restrict__ bias, int relu, int out_f32)
{
    const unsigned short* A = blockIdx.z ? A1 : A0;
    const unsigned short* Bt = blockIdx.z ? B1 : B0;
    void* C = blockIdx.z ? C1 : C0;

    constexpr int NI = BN / 32;   // N-frags per wave
    __shared__ unsigned short Als[128 * 32];
    __shared__ unsigned short Bls[BN * 32];
    int t = threadIdx.x;
    int lane = t & 63, w = t >> 6;
    int n0 = blockIdx.x * BN, m0 = blockIdx.y * 128;
    int wm = (w & 1) * 64, wn = (w >> 1) * (BN / 2);
    int lrow = lane & 15, quad = lane >> 4;

    f32x4 acc[4][NI];
    f32x4 z = {0.f, 0.f, 0.f, 0.f};
#pragma unroll
    for (int i = 0; i < 4; ++i)
#pragma unroll
        for (int j = 0; j < NI; ++j) acc[i][j] = z;

    int c0 = t, c1 = t + 256;
    const unsigned short* ag0 = A + (size_t)(m0 + (c0 >> 2)) * lda + (c0 & 3) * 8;
    const unsigned short* ag1 = A + (size_t)(m0 + (c1 >> 2)) * lda + (c1 & 3) * 8;
    const unsigned short* bg0 = Bt + (size_t)(n0 + (c0 >> 2)) * ldb + (c0 & 3) * 8;
    const unsigned short* bg1 = Bt + (size_t)(n0 + ((c1 >> 2) & (BN - 1))) * ldb + (c1 & 3) * 8;

    for (int k0 = 0; k0 < K; k0 += 32) {
        __syncthreads();
        load_lds16(ag0 + k0, &Als[c0 * 8]);
        load_lds16(ag1 + k0, &Als[c1 * 8]);
        load_lds16(bg0 + k0, &Bls[c0 * 8]);
        if constexpr (BN == 128) load_lds16(bg1 + k0, &Bls[c1 * 8]);
        __syncthreads();

        bf16x8 af[4], bfr[NI];
#pragma unroll
        for (int mi = 0; mi < 4; ++mi)
            af[mi] = *(const bf16x8*)&Als[(wm + mi * 16 + lrow) * 32 + quad * 8];
#pragma unroll
        for (int ni = 0; ni < NI; ++ni)
            bfr[ni] = *(const bf16x8*)&Bls[(wn + ni * 16 + lrow) * 32 + quad * 8];
#pragma unroll
        for (int mi = 0; mi < 4; ++mi)
#pragma unroll
            for (int ni = 0; ni < NI; ++ni)
                acc[mi][ni] = mfma_bf16(af[mi], bfr[ni], acc[mi][ni]);
    }

    if (OUTVT && blockIdx.z) {
        // transposed store: vt row = b*1024 + col, col index = n' (seq within batch)
        int bb = m0 >> 11;
        int npb = (m0 & 2047) + wm;
        unsigned short* vt = (unsigned short*)C;
#pragma unroll
        for (int mi = 0; mi < 4; ++mi)
#pragma unroll
            for (int ni = 0; ni < NI; ++ni) {
                int col = n0 + wn + ni * 16 + lrow;
                int np = npb + mi * 16 + quad * 4;
                ushort4 o;
                o.x = f2bfu(acc[mi][ni][0]);
                o.y = f2bfu(acc[mi][ni][1]);
                o.z = f2bfu(acc[mi][ni][2]);
                o.w = f2bfu(acc[mi][ni][3]);
                *(ushort4*)&vt[(size_t)(bb * 1024 + col) * 2048 + np] = o;
            }
        return;
    }

#pragma unroll
    for (int mi = 0; mi < 4; ++mi)
#pragma unroll
        for (int ni = 0; ni < NI; ++ni)
#pragma unroll
            for (int r = 0; r < 4; ++r) {
                int row = m0 + wm + mi * 16 + quad * 4 + r;
                int col = n0 + wn + ni * 16 + lrow;
                float v = acc[mi][ni][r];
                if (bias) v += bias[col];
                if (relu) v = fmaxf(v, 0.0f);
                if (out_f32) ((float*)C)[(size_t)row * ldc + col] = v;
                else ((unsigned short*)C)[(size_t)row * ldc + col] = f2bfu(v);
            }
}

// ---------------- MFMA flash attention v6 (unchanged from R12) ----------------
// Q (ldq, scaled by 0.125*log2e), K (ldk): head-interleaved; Vt [32*64][2048].
// grid 512 1D (XCD-swizzled), block 256 (4 waves). Wave w owns Q rows
// w*32..+31 as 2 q-subtiles of 16. KVBLK=64, K/V double-buffered;
// stage(t+1) issued before compute(t); ONE barrier per tile.
// Softmax log2-domain, defer-max THR=8, lane-partial l. P per-wave per-qb
// [16][64] hw, XOR swizzle byte^=(row&7)<<4 on write and read.
__global__ __launch_bounds__(256, 2) void flash_mfma_kernel(
    const unsigned short* __restrict__ Q, int ldq,
    const unsigned short* __restrict__ K, int ldk,
    const unsigned short* __restrict__ Vt, unsigned short* __restrict__ O)
{
    __shared__ __align__(16) unsigned short Kls[2][2 * 64 * 32]; // [buf][half d][64 kv][32 d] 8KB ea
    __shared__ __align__(16) unsigned short Vls[2][2 * 64 * 32]; // [buf][ks][64 d][32 kv]   8KB ea
    __shared__ __align__(16) unsigned short Pls[4][2][16 * 64];  // [wave][qb][16 q][64 kv] swz 16KB

    // XCD swizzle: 512 = 8 XCDs x 64; XCD c gets logical blocks [c*64,(c+1)*64)
    // = 4 consecutive bh (K/V working set < 4MB L2).
    int pbid = blockIdx.x;
    int lbid = (pbid >> 3) + (pbid & 7) * 64;
    int q0 = (lbid & 15) * 128, bh = lbid >> 4;
    int b = bh >> 4, h = bh & 15;
    int t = threadIdx.x;
    int lane = t & 63, w = t >> 6;
    int lrow = lane & 15, quad = lane >> 4;

    // Q fragments: 2 q-subtiles x 2 k-halves (A-layout: row=lrow, k=quad*8)
    bf16x8 qf[2][2];
#pragma unroll
    for (int qb = 0; qb < 2; ++qb) {
        const unsigned short* qrow =
            Q + (size_t)(b * 2048 + q0 + w * 32 + qb * 16 + lrow) * ldq + h * 64;
        qf[qb][0] = *(const bf16x8*)&qrow[quad * 8];
        qf[qb][1] = *(const bf16x8*)&qrow[32 + quad * 8];
    }

    f32x4 z = {0.f, 0.f, 0.f, 0.f};
    f32x4 acco[2][4];
    float m_run[2][4], l_run[2][4];
#pragma unroll
    for (int qb = 0; qb < 2; ++qb)
#pragma unroll
        for (int r = 0; r < 4; ++r) {
            acco[qb][r] = z;
            m_run[qb][r] = -1e30f;
            l_run[qb][r] = 0.f;   // lane-partial sum
        }

    // staging: thread t covers row t>>2 (0..63), segment (t&3)*8
    int row4 = t >> 2;
    int seg = (t & 3) * 8;
    const unsigned short* kg = K + (size_t)(b * 2048 + row4) * ldk + h * 64 + seg;
    const unsigned short* vg = Vt + (size_t)(bh * 64 + row4) * 2048 + seg;

    char* pb[2] = { (char*)&Pls[w][0][0], (char*)&Pls[w][1][0] };

    // prologue: stage tile 0 -> buf 0
    load_lds16(kg,      &Kls[0][t * 8]);
    load_lds16(kg + 32, &Kls[0][2048 + t * 8]);
    load_lds16(vg,      &Vls[0][t * 8]);
    load_lds16(vg + 32, &Vls[0][2048 + t * 8]);
    __syncthreads();

    int cur = 0;
    for (int kt = 0; kt < 2048; kt += 64) {
        // issue next-tile stage into buf cur^1; latency hides under compute
        if (kt + 64 < 2048) {
            const unsigned short* kgk = kg + (size_t)(kt + 64) * ldk;
            const unsigned short* vgk = vg + kt + 64;
            int nb = cur ^ 1;
            load_lds16(kgk,      &Kls[nb][t * 8]);
            load_lds16(kgk + 32, &Kls[nb][2048 + t * 8]);
            load_lds16(vgk,      &Vls[nb][t * 8]);
            load_lds16(vgk + 32, &Vls[nb][2048 + t * 8]);
        }

        // S = Q K^T : 32 q rows x 64 kv; K-frags shared across q-subtiles
        f32x4 s[2][4];
        __builtin_amdgcn_s_setprio(1);
#pragma unroll
        for (int kt8 = 0; kt8 < 4; ++kt8) {
            bf16x8 k0 = *(const bf16x8*)&Kls[cur][(kt8 * 16 + lrow) * 32 + quad * 8];
            bf16x8 k1 = *(const bf16x8*)&Kls[cur][2048 + (kt8 * 16 + lrow) * 32 + quad * 8];
            s[0][kt8] = mfma_bf16(qf[0][0], k0, z);
            s[0][kt8] = mfma_bf16(qf[0][1], k1, s[0][kt8]);
            s[1][kt8] = mfma_bf16(qf[1][0], k0, z);
            s[1][kt8] = mfma_bf16(qf[1][1], k1, s[1][kt8]);
        }
        __builtin_amdgcn_s_setprio(0);

        // per q-subtile: softmax (log2, defer-max) -> P (swizzled writes)
#pragma unroll
        for (int qb = 0; qb < 2; ++qb) {
            float pm[4];
#pragma unroll
            for (int r = 0; r < 4; ++r)
                pm[r] = fmaxf(fmaxf(s[qb][0][r], s[qb][1][r]),
                              fmaxf(s[qb][2][r], s[qb][3][r]));
            bool ok = (pm[0] <= m_run[qb][0] + 8.f) && (pm[1] <= m_run[qb][1] + 8.f)
                   && (pm[2] <= m_run[qb][2] + 8.f) && (pm[3] <= m_run[qb][3] + 8.f);
            if (!__all(ok)) {
                // rare path: full 16-lane max reduce + rescale
#pragma unroll
                for (int r = 0; r < 4; ++r) {
#pragma unroll
                    for (int off = 1; off < 16; off <<= 1)
                        pm[r] = fmaxf(pm[r], __shfl_xor(pm[r], off, 64));
                    float mnew = fmaxf(m_run[qb][r], pm[r]);
                    float al = exp2_fast(m_run[qb][r] - mnew);
                    m_run[qb][r] = mnew;
                    l_run[qb][r] *= al;
#pragma unroll
                    for (int nt = 0; nt < 4; ++nt) acco[qb][nt][r] *= al;
                }
            }
            // p = exp2(s - m), lane-partial l, P -> swizzled LDS (wave-local)
#pragma unroll
            for (int kt8 = 0; kt8 < 4; ++kt8)
#pragma unroll
                for (int r = 0; r < 4; ++r) {
                    float p = exp2_fast(s[qb][kt8][r] - m_run[qb][r]);
                    l_run[qb][r] += p;
                    int row = quad * 4 + r;
                    int boff = (row * 128 + (kt8 * 16 + lrow) * 2) ^ ((row & 7) << 4);
                    *(unsigned short*)(pb[qb] + boff) = f2bfu(p);
                }
        }

        // PV: V-frags shared across both q-subtiles; swizzled b128 P reads
        __builtin_amdgcn_s_setprio(1);
#pragma unroll
        for (int ks = 0; ks < 2; ++ks) {
            int rb = (lrow * 128 + ks * 64 + quad * 16) ^ ((lrow & 7) << 4);
            bf16x8 pf0 = *(const bf16x8*)(pb[0] + rb);
            bf16x8 pf1 = *(const bf16x8*)(pb[1] + rb);
#pragma unroll
            for (int nt = 0; nt < 4; ++nt) {
                bf16x8 vf = *(const bf16x8*)&Vls[cur][ks * 2048 + (nt * 16 + lrow) * 32 + quad * 8];
                acco[0][nt] = mfma_bf16(pf0, vf, acco[0][nt]);
                acco[1][nt] = mfma_bf16(pf1, vf, acco[1][nt]);
            }
        }
        __builtin_amdgcn_s_setprio(0);

        __syncthreads();   // drains vmcnt(0): next tile staged; buf[cur] free
        cur ^= 1;
    }

    // epilogue: reduce lane-partial l across the 16-lane row group, write O
#pragma unroll
    for (int qb = 0; qb < 2; ++qb)
#pragma unroll
        for (int r = 0; r < 4; ++r) {
            float lr = l_run[qb][r];
#pragma unroll
            for (int off = 1; off < 16; off <<= 1)
                lr += __shfl_xor(lr, off, 64);
            float rl = 1.0f / lr;
            int row = b * 2048 + q0 + w * 32 + qb * 16 + quad * 4 + r;
#pragma unroll
            for (int nt = 0; nt < 4; ++nt)
                O[(size_t)row * 1024 + h * 64 + nt * 16 + lrow] =
                    f2bfu(acco[qb][nt][r] * rl);
        }
}

// ---------------- launch ----------------

extern "C" void kernel_launch(void* const* d_in, const int* in_sizes, int n_in,
                              void* d_out, int out_size, void* d_ws, size_t ws_size,
                              hipStream_t stream) {
    const float* x   = (const float*)d_in[0];
    const float* Wq  = (const float*)d_in[1];
    const float* Wkv = (const float*)d_in[2];
    const float* Wk1 = (const float*)d_in[3];
    const float* Wk2 = (const float*)d_in[4];
    const float* Wv1 = (const float*)d_in[5];
    const float* Wv2 = (const float*)d_in[6];
    const float* Wo  = (const float*)d_in[7];
    const float* bo  = (const float*)d_in[8];
    float* out = (float*)d_out;

    unsigned short* p = (unsigned short*)d_ws;
    unsigned short* xb    = p; p += 4194304;   // [4096][1024]
    unsigned short* WqkvT = p; p += 3145728;   // [3072][1024]  (Wq^T scaled | Wkv^T)
    unsigned short* WoT   = p; p += 1048576;   // [1024][1024]
    unsigned short* Wk1T  = p; p += 524288;    // [512][1024]
    unsigned short* Wv1T  = p; p += 524288;    // [512][1024]
    unsigned short* Wk2T  = p; p += 524288;    // [1024][512]
    unsigned short* Wv2T  = p; p += 524288;    // [1024][512]
    unsigned short* qkv   = p; p += 12582912;  // [4096][3072]  (q | k-in | v-in)
    unsigned short* tmpb  = p; p += 4194304;   // [4096][1024]  (k1 | v1), reused as attn
    unsigned short* kvo   = p; p += 8388608;   // [4096][1024] k only now
    unsigned short* vtb   = p; p += 4194304;   // [32*64][2048]
    unsigned short* attnb = tmpb;              // alias: tmp dead after k2v2

    dim3 blk(256);
    const float qscale = 0.125f * 1.44269504f;  // Dh^-0.5 * log2(e)

    // prep: cvt_x (4096 blocks) + 4 weight transposes (1536 blocks), 1 launch
    prep_kernel<<<5632, blk, 0, stream>>>(
        x, xb, Wq, Wo, Wkv, Wk1, Wv1, Wk2, Wv2,
        WqkvT, WoT, Wk1T, Wv1T, Wk2T, Wv2T, qscale);

    // qkv = x @ [Wq*s | Wkv]   -> qkv [4096][3072]
    gemm_bf16_kernel<128><<<dim3(24, 32, 1), blk, 0, stream>>>(
        xb, xb, WqkvT, WqkvT, qkv, qkv, 1024, 1024, 3072, 1024, nullptr, 0, 0);
    // k1 = relu(kv_k @ Wk1), v1 = relu(kv_v @ Wv1)  -> tmpb [4096][512|512]
    gemm_bf16_kernel<64><<<dim3(8, 32, 2), blk, 0, stream>>>(
        qkv + 1024, qkv + 2048, Wk1T, Wv1T, tmpb, tmpb + 512,
        3072, 1024, 1024, 1024, nullptr, 1, 0);
    // k = k1 @ Wk2 -> kvo [4096][1024] (ldc=1024);
    // v = v1 @ Wv2 -> written TRANSPOSED straight into vtb (OUTVT, z=1)
    gemm_bf16_kernel<128, true><<<dim3(8, 32, 2), blk, 0, stream>>>(
        tmpb, tmpb + 512, Wk2T, Wv2T, kvo, vtb,
        1024, 512, 1024, 512, nullptr, 0, 0);

    flash_mfma_kernel<<<dim3(512), blk, 0, stream>>>(qkv, 3072, kvo, 1024, vtb, attnb);
    // out = attn @ Wo + bo (fp32), BN=64 for occupancy
    gemm_bf16_kernel<64><<<dim3(16, 32, 1), blk, 0, stream>>>(
        attnb, attnb, WoT, WoT, out, out, 1024, 1024, 1024, 1024, bo, 0, 1);
}

// Round 9
// 262.787 us; speedup vs baseline: 1.1601x; 1.0703x over previous
//
#include <hip/hip_runtime.h>
#include <stdint.h>

// MLA bf16-MFMA pipeline R14 (= R13 + weight reassociation):
// B=2, N=2048, D=1024, L=512, H=16, Dh=64.
// Since relu applies after @Wk1: relu((x@Wkv_k)@Wk1) = relu(x@(Wkv_k@Wk1)).
// Precompute WckT/WcvT = (Wkv_{k,v}@W{k,v}1)^T via small weight GEMMs into
// the stacked WqkvT rows [1024..2048), then ONE main GEMM
// [q|k1|v1] = x @ [Wq*s | Wck | Wcv]  (N=2048, relu for col>=1024).
// FLOPs: 34.4 GF (qkv+k1v1) -> 19.3 GF (2.1 weight + 17.2 main).
// Launches stay 6: prep, wGEMM, mainGEMM, k2v2(OUTVT), flash, out.
// Flash v6 unchanged from R12/R13 (71.5 µs invariant).
// MODEL NOTES (verified): SQ_LDS_BANK_CONFLICT = 4 x ds_read_b128 (b128 tax);
// flash neither latency- nor HBM-bound; XCD swizzle keeps FETCH at 12.3MB.

typedef __attribute__((ext_vector_type(8))) __bf16 bf16x8;
typedef __attribute__((ext_vector_type(4))) float f32x4;

__device__ inline unsigned short f2bfu(float f) {
    __bf16 b = (__bf16)f;
    return __builtin_bit_cast(unsigned short, b);
}

__device__ inline float exp2_fast(float f) {
    return __builtin_amdgcn_exp2f(f);   // raw v_exp_f32
}

__device__ inline void load_lds16(const void* g, void* l) {
    __builtin_amdgcn_global_load_lds(
        (const __attribute__((address_space(1))) uint32_t*)g,
        (__attribute__((address_space(3))) uint32_t*)l, 16, 0, 0);
}

__device__ inline f32x4 mfma_bf16(bf16x8 a, bf16x8 b, f32x4 c) {
    return __builtin_amdgcn_mfma_f32_16x16x32_bf16(a, b, c, 0, 0, 0);
}

// ---------------- merged prep kernel ----------------
// blocks [0,4096):      cvt x f32->bf16 (4 elems/thread)
// blocks [4096,6144):   cvt Wkv f32->bf16 (layout kept, [1024][2048])
// blocks [6144,7168):   weight transposes f32 [R][C] -> bf16 [C][R]*sc
__global__ __launch_bounds__(256) void prep_kernel(
    const float* __restrict__ x, unsigned short* __restrict__ xb,
    const float* __restrict__ Wkv, unsigned short* __restrict__ Wkvb,
    const float* __restrict__ Wq,  const float* __restrict__ Wo,
    const float* __restrict__ Wk1, const float* __restrict__ Wv1,
    const float* __restrict__ Wk2, const float* __restrict__ Wv2,
    unsigned short* __restrict__ WqkvT, unsigned short* __restrict__ WoT,
    unsigned short* __restrict__ Wk1T,  unsigned short* __restrict__ Wv1T,
    unsigned short* __restrict__ Wk2T,  unsigned short* __restrict__ Wv2T,
    float qscale)
{
    __shared__ float tile[64][65];
    int id = blockIdx.x;
    int t = threadIdx.x;

    if (id < 6144) {   // ---- elementwise cvt (x, Wkv) ----
        const float* s = (id < 4096) ? x : Wkv;
        unsigned short* d = (id < 4096) ? xb : Wkvb;
        int base = (id < 4096) ? id : (id - 4096);
        int i = (base * 256 + t) * 4;
        float4 v = *(const float4*)&s[i];
        ushort4 o;
        o.x = f2bfu(v.x); o.y = f2bfu(v.y); o.z = f2bfu(v.z); o.w = f2bfu(v.w);
        *(ushort4*)&d[i] = o;
        return;
    }

    // ---- transposes ----
    int r = id - 6144;
    const float* src; unsigned short* dst; int R, C; float sc; int bx, by;
    if (r < 512) {          // Wq / Wo : 16 x 16 x 2
        int z = r >> 8; int rr = r & 255; bx = rr & 15; by = rr >> 4;
        src = z ? Wo : Wq; dst = z ? WoT : WqkvT;
        R = 1024; C = 1024; sc = z ? 1.0f : qscale;
    } else if (r < 768) {   // Wk1 / Wv1 : 8 x 16 x 2
        int rr = r - 512; int z = rr >> 7; rr &= 127; bx = rr & 7; by = rr >> 3;
        src = z ? Wv1 : Wk1; dst = z ? Wv1T : Wk1T;
        R = 1024; C = 512; sc = 1.0f;
    } else {                // Wk2 / Wv2 : 16 x 8 x 2
        int rr = r - 768; int z = rr >> 7; rr &= 127; bx = rr & 15; by = rr >> 4;
        src = z ? Wv2 : Wk2; dst = z ? Wv2T : Wk2T;
        R = 512; C = 1024; sc = 1.0f;
    }

    int c0 = bx * 64, r0 = by * 64;
    int col = t & 63, rr4 = t >> 6;
#pragma unroll
    for (int i = 0; i < 16; ++i)
        tile[rr4 + i * 4][col] = src[(size_t)(r0 + rr4 + i * 4) * C + c0 + col];
    __syncthreads();
#pragma unroll
    for (int i = 0; i < 16; ++i) {
        int r2 = rr4 + i * 4;
        dst[(size_t)(c0 + r2) * R + r0 + col] = f2bfu(tile[col][r2] * sc);
    }
}

// ---------------- bf16 MFMA GEMM (m97 structure, z-batched, BN templated) ----
// C[M][N] = A[M][K] @ Bt[N][K]^T (+bias)(relu). 128xBN tile, BK=32.
// grid (N/BN, M/128, nz), block 256.
// relu: 0=none, 1=all, 2=only columns >= 1024.
// OUTVT: on the z=1 path, write C transposed into C1 as
// vt[(b*1024 + col) * 2048 + (m & 2047)] (b = m >> 11), b64-packed over r.
template<int BN, bool OUTVT = false>
__global__ __launch_bounds__(256) void gemm_bf16_kernel(
    const unsigned short* __restrict__ A0, const unsigned short* __restrict__ A1,
    const unsigned short* __restrict__ B0, const unsigned short* __restrict__ B1,
    void* __restrict__ C0, void* __restrict__ C1,
    int lda, int ldb, int ldc, int K,
    const float* __restrict__ bias, int relu, int out_f32)
{
    const unsigned short* A = blockIdx.z ? A1 : A0;
    const unsigned short* Bt = blockIdx.z ? B1 : B0;
    void* C = blockIdx.z ? C1 : C0;

    constexpr int NI = BN / 32;   // N-frags per wave
    __shared__ unsigned short Als[128 * 32];
    __shared__ unsigned short Bls[BN * 32];
    int t = threadIdx.x;
    int lane = t & 63, w = t >> 6;
    int n0 = blockIdx.x * BN, m0 = blockIdx.y * 128;
    int wm = (w & 1) * 64, wn = (w >> 1) * (BN / 2);
    int lrow = lane & 15, quad = lane >> 4;

    f32x4 acc[4][NI];
    f32x4 z = {0.f, 0.f, 0.f, 0.f};
#pragma unroll
    for (int i = 0; i < 4; ++i)
#pragma unroll
        for (int j = 0; j < NI; ++j) acc[i][j] = z;

    int c0 = t, c1 = t + 256;
    const unsigned short* ag0 = A + (size_t)(m0 + (c0 >> 2)) * lda + (c0 & 3) * 8;
    const unsigned short* ag1 = A + (size_t)(m0 + (c1 >> 2)) * lda + (c1 & 3) * 8;
    const unsigned short* bg0 = Bt + (size_t)(n0 + (c0 >> 2)) * ldb + (c0 & 3) * 8;
    const unsigned short* bg1 = Bt + (size_t)(n0 + ((c1 >> 2) & (BN - 1))) * ldb + (c1 & 3) * 8;

    for (int k0 = 0; k0 < K; k0 += 32) {
        __syncthreads();
        load_lds16(ag0 + k0, &Als[c0 * 8]);
        load_lds16(ag1 + k0, &Als[c1 * 8]);
        load_lds16(bg0 + k0, &Bls[c0 * 8]);
        if constexpr (BN == 128) load_lds16(bg1 + k0, &Bls[c1 * 8]);
        __syncthreads();

        bf16x8 af[4], bfr[NI];
#pragma unroll
        for (int mi = 0; mi < 4; ++mi)
            af[mi] = *(const bf16x8*)&Als[(wm + mi * 16 + lrow) * 32 + quad * 8];
#pragma unroll
        for (int ni = 0; ni < NI; ++ni)
            bfr[ni] = *(const bf16x8*)&Bls[(wn + ni * 16 + lrow) * 32 + quad * 8];
#pragma unroll
        for (int mi = 0; mi < 4; ++mi)
#pragma unroll
            for (int ni = 0; ni < NI; ++ni)
                acc[mi][ni] = mfma_bf16(af[mi], bfr[ni], acc[mi][ni]);
    }

    if (OUTVT && blockIdx.z) {
        // transposed store: vt row = b*1024 + col, col index = n' (seq within batch)
        int bb = m0 >> 11;
        int npb = (m0 & 2047) + wm;
        unsigned short* vt = (unsigned short*)C;
#pragma unroll
        for (int mi = 0; mi < 4; ++mi)
#pragma unroll
            for (int ni = 0; ni < NI; ++ni) {
                int col = n0 + wn + ni * 16 + lrow;
                int np = npb + mi * 16 + quad * 4;
                ushort4 o;
                o.x = f2bfu(acc[mi][ni][0]);
                o.y = f2bfu(acc[mi][ni][1]);
                o.z = f2bfu(acc[mi][ni][2]);
                o.w = f2bfu(acc[mi][ni][3]);
                *(ushort4*)&vt[(size_t)(bb * 1024 + col) * 2048 + np] = o;
            }
        return;
    }

#pragma unroll
    for (int mi = 0; mi < 4; ++mi)
#pragma unroll
        for (int ni = 0; ni < NI; ++ni)
#pragma unroll
            for (int r = 0; r < 4; ++r) {
                int row = m0 + wm + mi * 16 + quad * 4 + r;
                int col = n0 + wn + ni * 16 + lrow;
                float v = acc[mi][ni][r];
                if (bias) v += bias[col];
                if (relu == 1 || (relu == 2 && col >= 1024)) v = fmaxf(v, 0.0f);
                if (out_f32) ((float*)C)[(size_t)row * ldc + col] = v;
                else ((unsigned short*)C)[(size_t)row * ldc + col] = f2bfu(v);
            }
}

// ---------------- MFMA flash attention v6 (unchanged from R12) ----------------
// Q (ldq, scaled by 0.125*log2e), K (ldk): head-interleaved; Vt [32*64][2048].
// grid 512 1D (XCD-swizzled), block 256 (4 waves). Wave w owns Q rows
// w*32..+31 as 2 q-subtiles of 16. KVBLK=64, K/V double-buffered;
// stage(t+1) issued before compute(t); ONE barrier per tile.
// Softmax log2-domain, defer-max THR=8, lane-partial l. P per-wave per-qb
// [16][64] hw, XOR swizzle byte^=(row&7)<<4 on write and read.
__global__ __launch_bounds__(256, 2) void flash_mfma_kernel(
    const unsigned short* __restrict__ Q, int ldq,
    const unsigned short* __restrict__ K, int ldk,
    const unsigned short* __restrict__ Vt, unsigned short* __restrict__ O)
{
    __shared__ __align__(16) unsigned short Kls[2][2 * 64 * 32]; // [buf][half d][64 kv][32 d] 8KB ea
    __shared__ __align__(16) unsigned short Vls[2][2 * 64 * 32]; // [buf][ks][64 d][32 kv]   8KB ea
    __shared__ __align__(16) unsigned short Pls[4][2][16 * 64];  // [wave][qb][16 q][64 kv] swz 16KB

    // XCD swizzle: 512 = 8 XCDs x 64; XCD c gets logical blocks [c*64,(c+1)*64)
    // = 4 consecutive bh (K/V working set < 4MB L2).
    int pbid = blockIdx.x;
    int lbid = (pbid >> 3) + (pbid & 7) * 64;
    int q0 = (lbid & 15) * 128, bh = lbid >> 4;
    int b = bh >> 4, h = bh & 15;
    int t = threadIdx.x;
    int lane = t & 63, w = t >> 6;
    int lrow = lane & 15, quad = lane >> 4;

    // Q fragments: 2 q-subtiles x 2 k-halves (A-layout: row=lrow, k=quad*8)
    bf16x8 qf[2][2];
#pragma unroll
    for (int qb = 0; qb < 2; ++qb) {
        const unsigned short* qrow =
            Q + (size_t)(b * 2048 + q0 + w * 32 + qb * 16 + lrow) * ldq + h * 64;
        qf[qb][0] = *(const bf16x8*)&qrow[quad * 8];
        qf[qb][1] = *(const bf16x8*)&qrow[32 + quad * 8];
    }

    f32x4 z = {0.f, 0.f, 0.f, 0.f};
    f32x4 acco[2][4];
    float m_run[2][4], l_run[2][4];
#pragma unroll
    for (int qb = 0; qb < 2; ++qb)
#pragma unroll
        for (int r = 0; r < 4; ++r) {
            acco[qb][r] = z;
            m_run[qb][r] = -1e30f;
            l_run[qb][r] = 0.f;   // lane-partial sum
        }

    // staging: thread t covers row t>>2 (0..63), segment (t&3)*8
    int row4 = t >> 2;
    int seg = (t & 3) * 8;
    const unsigned short* kg = K + (size_t)(b * 2048 + row4) * ldk + h * 64 + seg;
    const unsigned short* vg = Vt + (size_t)(bh * 64 + row4) * 2048 + seg;

    char* pb[2] = { (char*)&Pls[w][0][0], (char*)&Pls[w][1][0] };

    // prologue: stage tile 0 -> buf 0
    load_lds16(kg,      &Kls[0][t * 8]);
    load_lds16(kg + 32, &Kls[0][2048 + t * 8]);
    load_lds16(vg,      &Vls[0][t * 8]);
    load_lds16(vg + 32, &Vls[0][2048 + t * 8]);
    __syncthreads();

    int cur = 0;
    for (int kt = 0; kt < 2048; kt += 64) {
        // issue next-tile stage into buf cur^1; latency hides under compute
        if (kt + 64 < 2048) {
            const unsigned short* kgk = kg + (size_t)(kt + 64) * ldk;
            const unsigned short* vgk = vg + kt + 64;
            int nb = cur ^ 1;
            load_lds16(kgk,      &Kls[nb][t * 8]);
            load_lds16(kgk + 32, &Kls[nb][2048 + t * 8]);
            load_lds16(vgk,      &Vls[nb][t * 8]);
            load_lds16(vgk + 32, &Vls[nb][2048 + t * 8]);
        }

        // S = Q K^T : 32 q rows x 64 kv; K-frags shared across q-subtiles
        f32x4 s[2][4];
        __builtin_amdgcn_s_setprio(1);
#pragma unroll
        for (int kt8 = 0; kt8 < 4; ++kt8) {
            bf16x8 k0 = *(const bf16x8*)&Kls[cur][(kt8 * 16 + lrow) * 32 + quad * 8];
            bf16x8 k1 = *(const bf16x8*)&Kls[cur][2048 + (kt8 * 16 + lrow) * 32 + quad * 8];
            s[0][kt8] = mfma_bf16(qf[0][0], k0, z);
            s[0][kt8] = mfma_bf16(qf[0][1], k1, s[0][kt8]);
            s[1][kt8] = mfma_bf16(qf[1][0], k0, z);
            s[1][kt8] = mfma_bf16(qf[1][1], k1, s[1][kt8]);
        }
        __builtin_amdgcn_s_setprio(0);

        // per q-subtile: softmax (log2, defer-max) -> P (swizzled writes)
#pragma unroll
        for (int qb = 0; qb < 2; ++qb) {
            float pm[4];
#pragma unroll
            for (int r = 0; r < 4; ++r)
                pm[r] = fmaxf(fmaxf(s[qb][0][r], s[qb][1][r]),
                              fmaxf(s[qb][2][r], s[qb][3][r]));
            bool ok = (pm[0] <= m_run[qb][0] + 8.f) && (pm[1] <= m_run[qb][1] + 8.f)
                   && (pm[2] <= m_run[qb][2] + 8.f) && (pm[3] <= m_run[qb][3] + 8.f);
            if (!__all(ok)) {
                // rare path: full 16-lane max reduce + rescale
#pragma unroll
                for (int r = 0; r < 4; ++r) {
#pragma unroll
                    for (int off = 1; off < 16; off <<= 1)
                        pm[r] = fmaxf(pm[r], __shfl_xor(pm[r], off, 64));
                    float mnew = fmaxf(m_run[qb][r], pm[r]);
                    float al = exp2_fast(m_run[qb][r] - mnew);
                    m_run[qb][r] = mnew;
                    l_run[qb][r] *= al;
#pragma unroll
                    for (int nt = 0; nt < 4; ++nt) acco[qb][nt][r] *= al;
                }
            }
            // p = exp2(s - m), lane-partial l, P -> swizzled LDS (wave-local)
#pragma unroll
            for (int kt8 = 0; kt8 < 4; ++kt8)
#pragma unroll
                for (int r = 0; r < 4; ++r) {
                    float p = exp2_fast(s[qb][kt8][r] - m_run[qb][r]);
                    l_run[qb][r] += p;
                    int row = quad * 4 + r;
                    int boff = (row * 128 + (kt8 * 16 + lrow) * 2) ^ ((row & 7) << 4);
                    *(unsigned short*)(pb[qb] + boff) = f2bfu(p);
                }
        }

        // PV: V-frags shared across both q-subtiles; swizzled b128 P reads
        __builtin_amdgcn_s_setprio(1);
#pragma unroll
        for (int ks = 0; ks < 2; ++ks) {
            int rb = (lrow * 128 + ks * 64 + quad * 16) ^ ((lrow & 7) << 4);
            bf16x8 pf0 = *(const bf16x8*)(pb[0] + rb);
            bf16x8 pf1 = *(const bf16x8*)(pb[1] + rb);
#pragma unroll
            for (int nt = 0; nt < 4; ++nt) {
                bf16x8 vf = *(const bf16x8*)&Vls[cur][ks * 2048 + (nt * 16 + lrow) * 32 + quad * 8];
                acco[0][nt] = mfma_bf16(pf0, vf, acco[0][nt]);
                acco[1][nt] = mfma_bf16(pf1, vf, acco[1][nt]);
            }
        }
        __builtin_amdgcn_s_setprio(0);

        __syncthreads();   // drains vmcnt(0): next tile staged; buf[cur] free
        cur ^= 1;
    }

    // epilogue: reduce lane-partial l across the 16-lane row group, write O
#pragma unroll
    for (int qb = 0; qb < 2; ++qb)
#pragma unroll
        for (int r = 0; r < 4; ++r) {
            float lr = l_run[qb][r];
#pragma unroll
            for (int off = 1; off < 16; off <<= 1)
                lr += __shfl_xor(lr, off, 64);
            float rl = 1.0f / lr;
            int row = b * 2048 + q0 + w * 32 + qb * 16 + quad * 4 + r;
#pragma unroll
            for (int nt = 0; nt < 4; ++nt)
                O[(size_t)row * 1024 + h * 64 + nt * 16 + lrow] =
                    f2bfu(acco[qb][nt][r] * rl);
        }
}

// ---------------- launch ----------------

extern "C" void kernel_launch(void* const* d_in, const int* in_sizes, int n_in,
                              void* d_out, int out_size, void* d_ws, size_t ws_size,
                              hipStream_t stream) {
    const float* x   = (const float*)d_in[0];
    const float* Wq  = (const float*)d_in[1];
    const float* Wkv = (const float*)d_in[2];
    const float* Wk1 = (const float*)d_in[3];
    const float* Wk2 = (const float*)d_in[4];
    const float* Wv1 = (const float*)d_in[5];
    const float* Wv2 = (const float*)d_in[6];
    const float* Wo  = (const float*)d_in[7];
    const float* bo  = (const float*)d_in[8];
    float* out = (float*)d_out;

    unsigned short* p = (unsigned short*)d_ws;
    unsigned short* xb    = p; p += 4194304;   // [4096][1024]
    unsigned short* Wkvb  = p; p += 2097152;   // [1024][2048] bf16, layout kept
    unsigned short* WqkvT = p; p += 2097152;   // [2048][1024]: WqT*s | WckT | WcvT
    unsigned short* WoT   = p; p += 1048576;   // [1024][1024]
    unsigned short* Wk1T  = p; p += 524288;    // [512][1024]
    unsigned short* Wv1T  = p; p += 524288;    // [512][1024]
    unsigned short* Wk2T  = p; p += 524288;    // [1024][512]
    unsigned short* Wv2T  = p; p += 524288;    // [1024][512]
    unsigned short* qkv2  = p; p += 8388608;   // [4096][2048]  (q | k1 | v1)
    unsigned short* attnb = p; p += 4194304;   // [4096][1024]
    unsigned short* kvo   = p; p += 4194304;   // [4096][1024]  k
    unsigned short* vtb   = p; p += 4194304;   // [32*64][2048]

    dim3 blk(256);
    const float qscale = 0.125f * 1.44269504f;  // Dh^-0.5 * log2(e)

    // prep: cvt_x (4096) + cvt_Wkv (2048) + transposes (1024) = 7168 blocks
    prep_kernel<<<7168, blk, 0, stream>>>(
        x, xb, Wkv, Wkvb, Wq, Wo, Wk1, Wv1, Wk2, Wv2,
        WqkvT, WoT, Wk1T, Wv1T, Wk2T, Wv2T, qscale);

    // WckT[512][1024] = Wk1T @ Wkv_k^T ; WcvT = Wv1T @ Wkv_v^T  (z-batched)
    // C[j][i] = sum_k Wk1T[j][k] * Wkv[i][k]  ->  A=W{k,v}1T, Bt=Wkvb(+1024)
    // written straight into WqkvT rows 1024.. / 1536..
    gemm_bf16_kernel<64><<<dim3(16, 4, 2), blk, 0, stream>>>(
        Wk1T, Wv1T, Wkvb, Wkvb + 1024,
        WqkvT + 1024 * 1024, WqkvT + 1536 * 1024,
        1024, 2048, 1024, 1024, nullptr, 0, 0);

    // [q | k1 | v1] = x @ [Wq*s | Wck | Wcv] -> qkv2 [4096][2048]; relu col>=1024
    gemm_bf16_kernel<128><<<dim3(16, 32, 1), blk, 0, stream>>>(
        xb, xb, WqkvT, WqkvT, qkv2, qkv2, 1024, 1024, 2048, 1024, nullptr, 2, 0);

    // k = k1 @ Wk2 -> kvo [4096][1024]; v = v1 @ Wv2 -> TRANSPOSED into vtb
    gemm_bf16_kernel<128, true><<<dim3(8, 32, 2), blk, 0, stream>>>(
        qkv2 + 1024, qkv2 + 1536, Wk2T, Wv2T, kvo, vtb,
        2048, 512, 1024, 512, nullptr, 0, 0);

    flash_mfma_kernel<<<dim3(512), blk, 0, stream>>>(qkv2, 2048, kvo, 1024, vtb, attnb);

    // out = attn @ Wo + bo (fp32), BN=64 for occupancy
    gemm_bf16_kernel<64><<<dim3(16, 32, 1), blk, 0, stream>>>(
        attnb, attnb, WoT, WoT, out, out, 1024, 1024, 1024, 1024, bo, 0, 1);
}

// Round 10
// 252.226 us; speedup vs baseline: 1.2087x; 1.0419x over previous
//
#include <hip/hip_runtime.h>
#include <stdint.h>

// MLA bf16-MFMA pipeline R15 (= R14 with BK=64 GEMM K-loop):
// B=2, N=2048, D=1024, L=512, H=16, Dh=64.
// GEMM: BK 32->64. LDS holds two [rows][32] half-tiles (concatenated, NOT a
// flat [rows][64] which would be a 16-way bank conflict on frag reads);
// staging issues both halves before ONE barrier -> vmcnt(0) barrier-drain
// count per block halves (the m97 structure's known ~20% stall). Inner loop
// = proven frag+MFMA body x2. LDS 32KB (BN=128) / 24KB (BN=64).
// Pipeline (R14): reassociated weights (Wck=Wkv_k@Wk1 etc), 6 launches:
// prep, wGEMM, mainGEMM(relu col>=1024), k2v2(OUTVT), flash, out.
// Flash v6 BYTE-IDENTICAL to R12/R13/R14 (72.8 µs invariant).
// MODEL NOTES (verified): SQ_LDS_BANK_CONFLICT = 4 x ds_read_b128 (b128 tax);
// flash neither latency- nor HBM-bound (dbuf null x2; XCD swizzle cut FETCH
// 5.7x, time flat).

typedef __attribute__((ext_vector_type(8))) __bf16 bf16x8;
typedef __attribute__((ext_vector_type(4))) float f32x4;

__device__ inline unsigned short f2bfu(float f) {
    __bf16 b = (__bf16)f;
    return __builtin_bit_cast(unsigned short, b);
}

__device__ inline float exp2_fast(float f) {
    return __builtin_amdgcn_exp2f(f);   // raw v_exp_f32
}

__device__ inline void load_lds16(const void* g, void* l) {
    __builtin_amdgcn_global_load_lds(
        (const __attribute__((address_space(1))) uint32_t*)g,
        (__attribute__((address_space(3))) uint32_t*)l, 16, 0, 0);
}

__device__ inline f32x4 mfma_bf16(bf16x8 a, bf16x8 b, f32x4 c) {
    return __builtin_amdgcn_mfma_f32_16x16x32_bf16(a, b, c, 0, 0, 0);
}

// ---------------- merged prep kernel ----------------
// blocks [0,4096):      cvt x f32->bf16 (4 elems/thread)
// blocks [4096,6144):   cvt Wkv f32->bf16 (layout kept, [1024][2048])
// blocks [6144,7168):   weight transposes f32 [R][C] -> bf16 [C][R]*sc
__global__ __launch_bounds__(256) void prep_kernel(
    const float* __restrict__ x, unsigned short* __restrict__ xb,
    const float* __restrict__ Wkv, unsigned short* __restrict__ Wkvb,
    const float* __restrict__ Wq,  const float* __restrict__ Wo,
    const float* __restrict__ Wk1, const float* __restrict__ Wv1,
    const float* __restrict__ Wk2, const float* __restrict__ Wv2,
    unsigned short* __restrict__ WqkvT, unsigned short* __restrict__ WoT,
    unsigned short* __restrict__ Wk1T,  unsigned short* __restrict__ Wv1T,
    unsigned short* __restrict__ Wk2T,  unsigned short* __restrict__ Wv2T,
    float qscale)
{
    __shared__ float tile[64][65];
    int id = blockIdx.x;
    int t = threadIdx.x;

    if (id < 6144) {   // ---- elementwise cvt (x, Wkv) ----
        const float* s = (id < 4096) ? x : Wkv;
        unsigned short* d = (id < 4096) ? xb : Wkvb;
        int base = (id < 4096) ? id : (id - 4096);
        int i = (base * 256 + t) * 4;
        float4 v = *(const float4*)&s[i];
        ushort4 o;
        o.x = f2bfu(v.x); o.y = f2bfu(v.y); o.z = f2bfu(v.z); o.w = f2bfu(v.w);
        *(ushort4*)&d[i] = o;
        return;
    }

    // ---- transposes ----
    int r = id - 6144;
    const float* src; unsigned short* dst; int R, C; float sc; int bx, by;
    if (r < 512) {          // Wq / Wo : 16 x 16 x 2
        int z = r >> 8; int rr = r & 255; bx = rr & 15; by = rr >> 4;
        src = z ? Wo : Wq; dst = z ? WoT : WqkvT;
        R = 1024; C = 1024; sc = z ? 1.0f : qscale;
    } else if (r < 768) {   // Wk1 / Wv1 : 8 x 16 x 2
        int rr = r - 512; int z = rr >> 7; rr &= 127; bx = rr & 7; by = rr >> 3;
        src = z ? Wv1 : Wk1; dst = z ? Wv1T : Wk1T;
        R = 1024; C = 512; sc = 1.0f;
    } else {                // Wk2 / Wv2 : 16 x 8 x 2
        int rr = r - 768; int z = rr >> 7; rr &= 127; bx = rr & 15; by = rr >> 4;
        src = z ? Wv2 : Wk2; dst = z ? Wv2T : Wk2T;
        R = 512; C = 1024; sc = 1.0f;
    }

    int c0 = bx * 64, r0 = by * 64;
    int col = t & 63, rr4 = t >> 6;
#pragma unroll
    for (int i = 0; i < 16; ++i)
        tile[rr4 + i * 4][col] = src[(size_t)(r0 + rr4 + i * 4) * C + c0 + col];
    __syncthreads();
#pragma unroll
    for (int i = 0; i < 16; ++i) {
        int r2 = rr4 + i * 4;
        dst[(size_t)(c0 + r2) * R + r0 + col] = f2bfu(tile[col][r2] * sc);
    }
}

// ---------------- bf16 MFMA GEMM (m97 structure, BK=64, BN templated) ------
// C[M][N] = A[M][K] @ Bt[N][K]^T (+bias)(relu). 128xBN tile, BK=64 as two
// [rows][32] half-tiles. grid (N/BN, M/128, nz), block 256. K % 64 == 0.
// relu: 0=none, 1=all, 2=only columns >= 1024.
// OUTVT: on the z=1 path, write C transposed into C1 as
// vt[(b*1024 + col) * 2048 + (m & 2047)] (b = m >> 11), b64-packed over r.
template<int BN, bool OUTVT = false>
__global__ __launch_bounds__(256) void gemm_bf16_kernel(
    const unsigned short* __restrict__ A0, const unsigned short* __restrict__ A1,
    const unsigned short* __restrict__ B0, const unsigned short* __restrict__ B1,
    void* __restrict__ C0, void* __restrict__ C1,
    int lda, int ldb, int ldc, int K,
    const float* __restrict__ bias, int relu, int out_f32)
{
    const unsigned short* A = blockIdx.z ? A1 : A0;
    const unsigned short* Bt = blockIdx.z ? B1 : B0;
    void* C = blockIdx.z ? C1 : C0;

    constexpr int NI = BN / 32;        // N-frags per wave
    constexpr int BH = BN * 32;        // halfwords per B half-tile
    __shared__ unsigned short Als[2 * 128 * 32];
    __shared__ unsigned short Bls[2 * BH];
    int t = threadIdx.x;
    int lane = t & 63, w = t >> 6;
    int n0 = blockIdx.x * BN, m0 = blockIdx.y * 128;
    int wm = (w & 1) * 64, wn = (w >> 1) * (BN / 2);
    int lrow = lane & 15, quad = lane >> 4;

    f32x4 acc[4][NI];
    f32x4 z = {0.f, 0.f, 0.f, 0.f};
#pragma unroll
    for (int i = 0; i < 4; ++i)
#pragma unroll
        for (int j = 0; j < NI; ++j) acc[i][j] = z;

    int c0 = t, c1 = t + 256;
    const unsigned short* ag0 = A + (size_t)(m0 + (c0 >> 2)) * lda + (c0 & 3) * 8;
    const unsigned short* ag1 = A + (size_t)(m0 + (c1 >> 2)) * lda + (c1 & 3) * 8;
    const unsigned short* bg0 = Bt + (size_t)(n0 + (c0 >> 2)) * ldb + (c0 & 3) * 8;
    const unsigned short* bg1 = Bt + (size_t)(n0 + ((c1 >> 2) & (BN - 1))) * ldb + (c1 & 3) * 8;

    for (int k0 = 0; k0 < K; k0 += 64) {
        __syncthreads();
        // half 0 (k0..k0+31) and half 1 (k0+32..k0+63), one barrier for both
        load_lds16(ag0 + k0,      &Als[c0 * 8]);
        load_lds16(ag1 + k0,      &Als[c1 * 8]);
        load_lds16(ag0 + k0 + 32, &Als[4096 + c0 * 8]);
        load_lds16(ag1 + k0 + 32, &Als[4096 + c1 * 8]);
        load_lds16(bg0 + k0,      &Bls[c0 * 8]);
        load_lds16(bg0 + k0 + 32, &Bls[BH + c0 * 8]);
        if constexpr (BN == 128) {
            load_lds16(bg1 + k0,      &Bls[c1 * 8]);
            load_lds16(bg1 + k0 + 32, &Bls[BH + c1 * 8]);
        }
        __syncthreads();

#pragma unroll
        for (int kk = 0; kk < 2; ++kk) {
            bf16x8 af[4], bfr[NI];
#pragma unroll
            for (int mi = 0; mi < 4; ++mi)
                af[mi] = *(const bf16x8*)&Als[kk * 4096 + (wm + mi * 16 + lrow) * 32 + quad * 8];
#pragma unroll
            for (int ni = 0; ni < NI; ++ni)
                bfr[ni] = *(const bf16x8*)&Bls[kk * BH + (wn + ni * 16 + lrow) * 32 + quad * 8];
#pragma unroll
            for (int mi = 0; mi < 4; ++mi)
#pragma unroll
                for (int ni = 0; ni < NI; ++ni)
                    acc[mi][ni] = mfma_bf16(af[mi], bfr[ni], acc[mi][ni]);
        }
    }

    if (OUTVT && blockIdx.z) {
        // transposed store: vt row = b*1024 + col, col index = n' (seq within batch)
        int bb = m0 >> 11;
        int npb = (m0 & 2047) + wm;
        unsigned short* vt = (unsigned short*)C;
#pragma unroll
        for (int mi = 0; mi < 4; ++mi)
#pragma unroll
            for (int ni = 0; ni < NI; ++ni) {
                int col = n0 + wn + ni * 16 + lrow;
                int np = npb + mi * 16 + quad * 4;
                ushort4 o;
                o.x = f2bfu(acc[mi][ni][0]);
                o.y = f2bfu(acc[mi][ni][1]);
                o.z = f2bfu(acc[mi][ni][2]);
                o.w = f2bfu(acc[mi][ni][3]);
                *(ushort4*)&vt[(size_t)(bb * 1024 + col) * 2048 + np] = o;
            }
        return;
    }

#pragma unroll
    for (int mi = 0; mi < 4; ++mi)
#pragma unroll
        for (int ni = 0; ni < NI; ++ni)
#pragma unroll
            for (int r = 0; r < 4; ++r) {
                int row = m0 + wm + mi * 16 + quad * 4 + r;
                int col = n0 + wn + ni * 16 + lrow;
                float v = acc[mi][ni][r];
                if (bias) v += bias[col];
                if (relu == 1 || (relu == 2 && col >= 1024)) v = fmaxf(v, 0.0f);
                if (out_f32) ((float*)C)[(size_t)row * ldc + col] = v;
                else ((unsigned short*)C)[(size_t)row * ldc + col] = f2bfu(v);
            }
}

// ---------------- MFMA flash attention v6 (unchanged from R12) ----------------
// Q (ldq, scaled by 0.125*log2e), K (ldk): head-interleaved; Vt [32*64][2048].
// grid 512 1D (XCD-swizzled), block 256 (4 waves). Wave w owns Q rows
// w*32..+31 as 2 q-subtiles of 16. KVBLK=64, K/V double-buffered;
// stage(t+1) issued before compute(t); ONE barrier per tile.
// Softmax log2-domain, defer-max THR=8, lane-partial l. P per-wave per-qb
// [16][64] hw, XOR swizzle byte^=(row&7)<<4 on write and read.
__global__ __launch_bounds__(256, 2) void flash_mfma_kernel(
    const unsigned short* __restrict__ Q, int ldq,
    const unsigned short* __restrict__ K, int ldk,
    const unsigned short* __restrict__ Vt, unsigned short* __restrict__ O)
{
    __shared__ __align__(16) unsigned short Kls[2][2 * 64 * 32]; // [buf][half d][64 kv][32 d] 8KB ea
    __shared__ __align__(16) unsigned short Vls[2][2 * 64 * 32]; // [buf][ks][64 d][32 kv]   8KB ea
    __shared__ __align__(16) unsigned short Pls[4][2][16 * 64];  // [wave][qb][16 q][64 kv] swz 16KB

    // XCD swizzle: 512 = 8 XCDs x 64; XCD c gets logical blocks [c*64,(c+1)*64)
    // = 4 consecutive bh (K/V working set < 4MB L2).
    int pbid = blockIdx.x;
    int lbid = (pbid >> 3) + (pbid & 7) * 64;
    int q0 = (lbid & 15) * 128, bh = lbid >> 4;
    int b = bh >> 4, h = bh & 15;
    int t = threadIdx.x;
    int lane = t & 63, w = t >> 6;
    int lrow = lane & 15, quad = lane >> 4;

    // Q fragments: 2 q-subtiles x 2 k-halves (A-layout: row=lrow, k=quad*8)
    bf16x8 qf[2][2];
#pragma unroll
    for (int qb = 0; qb < 2; ++qb) {
        const unsigned short* qrow =
            Q + (size_t)(b * 2048 + q0 + w * 32 + qb * 16 + lrow) * ldq + h * 64;
        qf[qb][0] = *(const bf16x8*)&qrow[quad * 8];
        qf[qb][1] = *(const bf16x8*)&qrow[32 + quad * 8];
    }

    f32x4 z = {0.f, 0.f, 0.f, 0.f};
    f32x4 acco[2][4];
    float m_run[2][4], l_run[2][4];
#pragma unroll
    for (int qb = 0; qb < 2; ++qb)
#pragma unroll
        for (int r = 0; r < 4; ++r) {
            acco[qb][r] = z;
            m_run[qb][r] = -1e30f;
            l_run[qb][r] = 0.f;   // lane-partial sum
        }

    // staging: thread t covers row t>>2 (0..63), segment (t&3)*8
    int row4 = t >> 2;
    int seg = (t & 3) * 8;
    const unsigned short* kg = K + (size_t)(b * 2048 + row4) * ldk + h * 64 + seg;
    const unsigned short* vg = Vt + (size_t)(bh * 64 + row4) * 2048 + seg;

    char* pb[2] = { (char*)&Pls[w][0][0], (char*)&Pls[w][1][0] };

    // prologue: stage tile 0 -> buf 0
    load_lds16(kg,      &Kls[0][t * 8]);
    load_lds16(kg + 32, &Kls[0][2048 + t * 8]);
    load_lds16(vg,      &Vls[0][t * 8]);
    load_lds16(vg + 32, &Vls[0][2048 + t * 8]);
    __syncthreads();

    int cur = 0;
    for (int kt = 0; kt < 2048; kt += 64) {
        // issue next-tile stage into buf cur^1; latency hides under compute
        if (kt + 64 < 2048) {
            const unsigned short* kgk = kg + (size_t)(kt + 64) * ldk;
            const unsigned short* vgk = vg + kt + 64;
            int nb = cur ^ 1;
            load_lds16(kgk,      &Kls[nb][t * 8]);
            load_lds16(kgk + 32, &Kls[nb][2048 + t * 8]);
            load_lds16(vgk,      &Vls[nb][t * 8]);
            load_lds16(vgk + 32, &Vls[nb][2048 + t * 8]);
        }

        // S = Q K^T : 32 q rows x 64 kv; K-frags shared across q-subtiles
        f32x4 s[2][4];
        __builtin_amdgcn_s_setprio(1);
#pragma unroll
        for (int kt8 = 0; kt8 < 4; ++kt8) {
            bf16x8 k0 = *(const bf16x8*)&Kls[cur][(kt8 * 16 + lrow) * 32 + quad * 8];
            bf16x8 k1 = *(const bf16x8*)&Kls[cur][2048 + (kt8 * 16 + lrow) * 32 + quad * 8];
            s[0][kt8] = mfma_bf16(qf[0][0], k0, z);
            s[0][kt8] = mfma_bf16(qf[0][1], k1, s[0][kt8]);
            s[1][kt8] = mfma_bf16(qf[1][0], k0, z);
            s[1][kt8] = mfma_bf16(qf[1][1], k1, s[1][kt8]);
        }
        __builtin_amdgcn_s_setprio(0);

        // per q-subtile: softmax (log2, defer-max) -> P (swizzled writes)
#pragma unroll
        for (int qb = 0; qb < 2; ++qb) {
            float pm[4];
#pragma unroll
            for (int r = 0; r < 4; ++r)
                pm[r] = fmaxf(fmaxf(s[qb][0][r], s[qb][1][r]),
                              fmaxf(s[qb][2][r], s[qb][3][r]));
            bool ok = (pm[0] <= m_run[qb][0] + 8.f) && (pm[1] <= m_run[qb][1] + 8.f)
                   && (pm[2] <= m_run[qb][2] + 8.f) && (pm[3] <= m_run[qb][3] + 8.f);
            if (!__all(ok)) {
                // rare path: full 16-lane max reduce + rescale
#pragma unroll
                for (int r = 0; r < 4; ++r) {
#pragma unroll
                    for (int off = 1; off < 16; off <<= 1)
                        pm[r] = fmaxf(pm[r], __shfl_xor(pm[r], off, 64));
                    float mnew = fmaxf(m_run[qb][r], pm[r]);
                    float al = exp2_fast(m_run[qb][r] - mnew);
                    m_run[qb][r] = mnew;
                    l_run[qb][r] *= al;
#pragma unroll
                    for (int nt = 0; nt < 4; ++nt) acco[qb][nt][r] *= al;
                }
            }
            // p = exp2(s - m), lane-partial l, P -> swizzled LDS (wave-local)
#pragma unroll
            for (int kt8 = 0; kt8 < 4; ++kt8)
#pragma unroll
                for (int r = 0; r < 4; ++r) {
                    float p = exp2_fast(s[qb][kt8][r] - m_run[qb][r]);
                    l_run[qb][r] += p;
                    int row = quad * 4 + r;
                    int boff = (row * 128 + (kt8 * 16 + lrow) * 2) ^ ((row & 7) << 4);
                    *(unsigned short*)(pb[qb] + boff) = f2bfu(p);
                }
        }

        // PV: V-frags shared across both q-subtiles; swizzled b128 P reads
        __builtin_amdgcn_s_setprio(1);
#pragma unroll
        for (int ks = 0; ks < 2; ++ks) {
            int rb = (lrow * 128 + ks * 64 + quad * 16) ^ ((lrow & 7) << 4);
            bf16x8 pf0 = *(const bf16x8*)(pb[0] + rb);
            bf16x8 pf1 = *(const bf16x8*)(pb[1] + rb);
#pragma unroll
            for (int nt = 0; nt < 4; ++nt) {
                bf16x8 vf = *(const bf16x8*)&Vls[cur][ks * 2048 + (nt * 16 + lrow) * 32 + quad * 8];
                acco[0][nt] = mfma_bf16(pf0, vf, acco[0][nt]);
                acco[1][nt] = mfma_bf16(pf1, vf, acco[1][nt]);
            }
        }
        __builtin_amdgcn_s_setprio(0);

        __syncthreads();   // drains vmcnt(0): next tile staged; buf[cur] free
        cur ^= 1;
    }

    // epilogue: reduce lane-partial l across the 16-lane row group, write O
#pragma unroll
    for (int qb = 0; qb < 2; ++qb)
#pragma unroll
        for (int r = 0; r < 4; ++r) {
            float lr = l_run[qb][r];
#pragma unroll
            for (int off = 1; off < 16; off <<= 1)
                lr += __shfl_xor(lr, off, 64);
            float rl = 1.0f / lr;
            int row = b * 2048 + q0 + w * 32 + qb * 16 + quad * 4 + r;
#pragma unroll
            for (int nt = 0; nt < 4; ++nt)
                O[(size_t)row * 1024 + h * 64 + nt * 16 + lrow] =
                    f2bfu(acco[qb][nt][r] * rl);
        }
}

// ---------------- launch ----------------

extern "C" void kernel_launch(void* const* d_in, const int* in_sizes, int n_in,
                              void* d_out, int out_size, void* d_ws, size_t ws_size,
                              hipStream_t stream) {
    const float* x   = (const float*)d_in[0];
    const float* Wq  = (const float*)d_in[1];
    const float* Wkv = (const float*)d_in[2];
    const float* Wk1 = (const float*)d_in[3];
    const float* Wk2 = (const float*)d_in[4];
    const float* Wv1 = (const float*)d_in[5];
    const float* Wv2 = (const float*)d_in[6];
    const float* Wo  = (const float*)d_in[7];
    const float* bo  = (const float*)d_in[8];
    float* out = (float*)d_out;

    unsigned short* p = (unsigned short*)d_ws;
    unsigned short* xb    = p; p += 4194304;   // [4096][1024]
    unsigned short* Wkvb  = p; p += 2097152;   // [1024][2048] bf16, layout kept
    unsigned short* WqkvT = p; p += 2097152;   // [2048][1024]: WqT*s | WckT | WcvT
    unsigned short* WoT   = p; p += 1048576;   // [1024][1024]
    unsigned short* Wk1T  = p; p += 524288;    // [512][1024]
    unsigned short* Wv1T  = p; p += 524288;    // [512][1024]
    unsigned short* Wk2T  = p; p += 524288;    // [1024][512]
    unsigned short* Wv2T  = p; p += 524288;    // [1024][512]
    unsigned short* qkv2  = p; p += 8388608;   // [4096][2048]  (q | k1 | v1)
    unsigned short* attnb = p; p += 4194304;   // [4096][1024]
    unsigned short* kvo   = p; p += 4194304;   // [4096][1024]  k
    unsigned short* vtb   = p; p += 4194304;   // [32*64][2048]

    dim3 blk(256);
    const float qscale = 0.125f * 1.44269504f;  // Dh^-0.5 * log2(e)

    // prep: cvt_x (4096) + cvt_Wkv (2048) + transposes (1024) = 7168 blocks
    prep_kernel<<<7168, blk, 0, stream>>>(
        x, xb, Wkv, Wkvb, Wq, Wo, Wk1, Wv1, Wk2, Wv2,
        WqkvT, WoT, Wk1T, Wv1T, Wk2T, Wv2T, qscale);

    // WckT[512][1024] = Wk1T @ Wkv_k^T ; WcvT = Wv1T @ Wkv_v^T  (z-batched)
    gemm_bf16_kernel<64><<<dim3(16, 4, 2), blk, 0, stream>>>(
        Wk1T, Wv1T, Wkvb, Wkvb + 1024,
        WqkvT + 1024 * 1024, WqkvT + 1536 * 1024,
        1024, 2048, 1024, 1024, nullptr, 0, 0);

    // [q | k1 | v1] = x @ [Wq*s | Wck | Wcv] -> qkv2 [4096][2048]; relu col>=1024
    gemm_bf16_kernel<128><<<dim3(16, 32, 1), blk, 0, stream>>>(
        xb, xb, WqkvT, WqkvT, qkv2, qkv2, 1024, 1024, 2048, 1024, nullptr, 2, 0);

    // k = k1 @ Wk2 -> kvo [4096][1024]; v = v1 @ Wv2 -> TRANSPOSED into vtb
    gemm_bf16_kernel<128, true><<<dim3(8, 32, 2), blk, 0, stream>>>(
        qkv2 + 1024, qkv2 + 1536, Wk2T, Wv2T, kvo, vtb,
        2048, 512, 1024, 512, nullptr, 0, 0);

    flash_mfma_kernel<<<dim3(512), blk, 0, stream>>>(qkv2, 2048, kvo, 1024, vtb, attnb);

    // out = attn @ Wo + bo (fp32), BN=64 for occupancy
    gemm_bf16_kernel<64><<<dim3(16, 32, 1), blk, 0, stream>>>(
        attnb, attnb, WoT, WoT, out, out, 1024, 1024, 1024, 1024, bo, 0, 1);
}

// Round 11
// 241.089 us; speedup vs baseline: 1.2645x; 1.0462x over previous
//
#include <hip/hip_runtime.h>
#include <stdint.h>

// MLA bf16-MFMA pipeline R16 (= R15 with BK=128 GEMM K-loop):
// B=2, N=2048, D=1024, L=512, H=16, Dh=64.
// GEMM: BK 64->128 as FOUR [rows][32] sub-chunks (conflict-free stride-32
// fragment reads preserved); all 12-16 global_load_lds issued before ONE
// barrier -> vmcnt(0) barrier-drain count per block halves again
// (main 16->8, k2v2 8->4, out 16->8). LDS 64KB (BN=128) / 48KB (BN=64);
// GEMMs are grid-limited at 2 blocks/CU so no occupancy change (m132's
// BK=128 regression was a 3->2 occupancy loss - doesn't apply here).
// R15 result: BK 32->64 = -10.6 us (drain theory confirmed).
// Pipeline (R14): reassociated weights, 6 launches:
// prep, wGEMM, mainGEMM(relu col>=1024), k2v2(OUTVT), flash, out.
// Flash v6 BYTE-IDENTICAL to R12-R15 (71.8 us invariant, 7 rounds).
// MODEL NOTES (verified): SQ_LDS_BANK_CONFLICT = 4 x ds_read_b128 (b128 tax);
// flash neither latency- nor HBM-bound (dbuf null x2; XCD swizzle cut FETCH
// 5.7x, time flat); flash floor ~10.8K cyc/CU-tile, no pipe >40%.

typedef __attribute__((ext_vector_type(8))) __bf16 bf16x8;
typedef __attribute__((ext_vector_type(4))) float f32x4;

__device__ inline unsigned short f2bfu(float f) {
    __bf16 b = (__bf16)f;
    return __builtin_bit_cast(unsigned short, b);
}

__device__ inline float exp2_fast(float f) {
    return __builtin_amdgcn_exp2f(f);   // raw v_exp_f32
}

__device__ inline void load_lds16(const void* g, void* l) {
    __builtin_amdgcn_global_load_lds(
        (const __attribute__((address_space(1))) uint32_t*)g,
        (__attribute__((address_space(3))) uint32_t*)l, 16, 0, 0);
}

__device__ inline f32x4 mfma_bf16(bf16x8 a, bf16x8 b, f32x4 c) {
    return __builtin_amdgcn_mfma_f32_16x16x32_bf16(a, b, c, 0, 0, 0);
}

// ---------------- merged prep kernel ----------------
// blocks [0,4096):      cvt x f32->bf16 (4 elems/thread)
// blocks [4096,6144):   cvt Wkv f32->bf16 (layout kept, [1024][2048])
// blocks [6144,7168):   weight transposes f32 [R][C] -> bf16 [C][R]*sc
__global__ __launch_bounds__(256) void prep_kernel(
    const float* __restrict__ x, unsigned short* __restrict__ xb,
    const float* __restrict__ Wkv, unsigned short* __restrict__ Wkvb,
    const float* __restrict__ Wq,  const float* __restrict__ Wo,
    const float* __restrict__ Wk1, const float* __restrict__ Wv1,
    const float* __restrict__ Wk2, const float* __restrict__ Wv2,
    unsigned short* __restrict__ WqkvT, unsigned short* __restrict__ WoT,
    unsigned short* __restrict__ Wk1T,  unsigned short* __restrict__ Wv1T,
    unsigned short* __restrict__ Wk2T,  unsigned short* __restrict__ Wv2T,
    float qscale)
{
    __shared__ float tile[64][65];
    int id = blockIdx.x;
    int t = threadIdx.x;

    if (id < 6144) {   // ---- elementwise cvt (x, Wkv) ----
        const float* s = (id < 4096) ? x : Wkv;
        unsigned short* d = (id < 4096) ? xb : Wkvb;
        int base = (id < 4096) ? id : (id - 4096);
        int i = (base * 256 + t) * 4;
        float4 v = *(const float4*)&s[i];
        ushort4 o;
        o.x = f2bfu(v.x); o.y = f2bfu(v.y); o.z = f2bfu(v.z); o.w = f2bfu(v.w);
        *(ushort4*)&d[i] = o;
        return;
    }

    // ---- transposes ----
    int r = id - 6144;
    const float* src; unsigned short* dst; int R, C; float sc; int bx, by;
    if (r < 512) {          // Wq / Wo : 16 x 16 x 2
        int z = r >> 8; int rr = r & 255; bx = rr & 15; by = rr >> 4;
        src = z ? Wo : Wq; dst = z ? WoT : WqkvT;
        R = 1024; C = 1024; sc = z ? 1.0f : qscale;
    } else if (r < 768) {   // Wk1 / Wv1 : 8 x 16 x 2
        int rr = r - 512; int z = rr >> 7; rr &= 127; bx = rr & 7; by = rr >> 3;
        src = z ? Wv1 : Wk1; dst = z ? Wv1T : Wk1T;
        R = 1024; C = 512; sc = 1.0f;
    } else {                // Wk2 / Wv2 : 16 x 8 x 2
        int rr = r - 768; int z = rr >> 7; rr &= 127; bx = rr & 15; by = rr >> 4;
        src = z ? Wv2 : Wk2; dst = z ? Wv2T : Wk2T;
        R = 512; C = 1024; sc = 1.0f;
    }

    int c0 = bx * 64, r0 = by * 64;
    int col = t & 63, rr4 = t >> 6;
#pragma unroll
    for (int i = 0; i < 16; ++i)
        tile[rr4 + i * 4][col] = src[(size_t)(r0 + rr4 + i * 4) * C + c0 + col];
    __syncthreads();
#pragma unroll
    for (int i = 0; i < 16; ++i) {
        int r2 = rr4 + i * 4;
        dst[(size_t)(c0 + r2) * R + r0 + col] = f2bfu(tile[col][r2] * sc);
    }
}

// ---------------- bf16 MFMA GEMM (m97 structure, BK=128, BN templated) -----
// C[M][N] = A[M][K] @ Bt[N][K]^T (+bias)(relu). 128xBN tile, BK=128 as four
// [rows][32] sub-chunks. grid (N/BN, M/128, nz), block 256. K % 128 == 0.
// relu: 0=none, 1=all, 2=only columns >= 1024.
// OUTVT: on the z=1 path, write C transposed into C1 as
// vt[(b*1024 + col) * 2048 + (m & 2047)] (b = m >> 11), b64-packed over r.
template<int BN, bool OUTVT = false>
__global__ __launch_bounds__(256) void gemm_bf16_kernel(
    const unsigned short* __restrict__ A0, const unsigned short* __restrict__ A1,
    const unsigned short* __restrict__ B0, const unsigned short* __restrict__ B1,
    void* __restrict__ C0, void* __restrict__ C1,
    int lda, int ldb, int ldc, int K,
    const float* __restrict__ bias, int relu, int out_f32)
{
    const unsigned short* A = blockIdx.z ? A1 : A0;
    const unsigned short* Bt = blockIdx.z ? B1 : B0;
    void* C = blockIdx.z ? C1 : C0;

    constexpr int NI = BN / 32;        // N-frags per wave
    constexpr int AH = 128 * 32;       // halfwords per A sub-chunk
    constexpr int BH = BN * 32;        // halfwords per B sub-chunk
    __shared__ unsigned short Als[4 * AH];
    __shared__ unsigned short Bls[4 * BH];
    int t = threadIdx.x;
    int lane = t & 63, w = t >> 6;
    int n0 = blockIdx.x * BN, m0 = blockIdx.y * 128;
    int wm = (w & 1) * 64, wn = (w >> 1) * (BN / 2);
    int lrow = lane & 15, quad = lane >> 4;

    f32x4 acc[4][NI];
    f32x4 z = {0.f, 0.f, 0.f, 0.f};
#pragma unroll
    for (int i = 0; i < 4; ++i)
#pragma unroll
        for (int j = 0; j < NI; ++j) acc[i][j] = z;

    int c0 = t, c1 = t + 256;
    const unsigned short* ag0 = A + (size_t)(m0 + (c0 >> 2)) * lda + (c0 & 3) * 8;
    const unsigned short* ag1 = A + (size_t)(m0 + (c1 >> 2)) * lda + (c1 & 3) * 8;
    const unsigned short* bg0 = Bt + (size_t)(n0 + (c0 >> 2)) * ldb + (c0 & 3) * 8;
    const unsigned short* bg1 = Bt + (size_t)(n0 + ((c1 >> 2) & (BN - 1))) * ldb + (c1 & 3) * 8;

    for (int k0 = 0; k0 < K; k0 += 128) {
        __syncthreads();
        // four 32-wide sub-chunks, one barrier for all
#pragma unroll
        for (int h = 0; h < 4; ++h) {
            load_lds16(ag0 + k0 + h * 32, &Als[h * AH + c0 * 8]);
            load_lds16(ag1 + k0 + h * 32, &Als[h * AH + c1 * 8]);
            load_lds16(bg0 + k0 + h * 32, &Bls[h * BH + c0 * 8]);
            if constexpr (BN == 128)
                load_lds16(bg1 + k0 + h * 32, &Bls[h * BH + c1 * 8]);
        }
        __syncthreads();

#pragma unroll
        for (int kk = 0; kk < 4; ++kk) {
            bf16x8 af[4], bfr[NI];
#pragma unroll
            for (int mi = 0; mi < 4; ++mi)
                af[mi] = *(const bf16x8*)&Als[kk * AH + (wm + mi * 16 + lrow) * 32 + quad * 8];
#pragma unroll
            for (int ni = 0; ni < NI; ++ni)
                bfr[ni] = *(const bf16x8*)&Bls[kk * BH + (wn + ni * 16 + lrow) * 32 + quad * 8];
#pragma unroll
            for (int mi = 0; mi < 4; ++mi)
#pragma unroll
                for (int ni = 0; ni < NI; ++ni)
                    acc[mi][ni] = mfma_bf16(af[mi], bfr[ni], acc[mi][ni]);
        }
    }

    if (OUTVT && blockIdx.z) {
        // transposed store: vt row = b*1024 + col, col index = n' (seq within batch)
        int bb = m0 >> 11;
        int npb = (m0 & 2047) + wm;
        unsigned short* vt = (unsigned short*)C;
#pragma unroll
        for (int mi = 0; mi < 4; ++mi)
#pragma unroll
            for (int ni = 0; ni < NI; ++ni) {
                int col = n0 + wn + ni * 16 + lrow;
                int np = npb + mi * 16 + quad * 4;
                ushort4 o;
                o.x = f2bfu(acc[mi][ni][0]);
                o.y = f2bfu(acc[mi][ni][1]);
                o.z = f2bfu(acc[mi][ni][2]);
                o.w = f2bfu(acc[mi][ni][3]);
                *(ushort4*)&vt[(size_t)(bb * 1024 + col) * 2048 + np] = o;
            }
        return;
    }

#pragma unroll
    for (int mi = 0; mi < 4; ++mi)
#pragma unroll
        for (int ni = 0; ni < NI; ++ni)
#pragma unroll
            for (int r = 0; r < 4; ++r) {
                int row = m0 + wm + mi * 16 + quad * 4 + r;
                int col = n0 + wn + ni * 16 + lrow;
                float v = acc[mi][ni][r];
                if (bias) v += bias[col];
                if (relu == 1 || (relu == 2 && col >= 1024)) v = fmaxf(v, 0.0f);
                if (out_f32) ((float*)C)[(size_t)row * ldc + col] = v;
                else ((unsigned short*)C)[(size_t)row * ldc + col] = f2bfu(v);
            }
}

// ---------------- MFMA flash attention v6 (unchanged from R12) ----------------
// Q (ldq, scaled by 0.125*log2e), K (ldk): head-interleaved; Vt [32*64][2048].
// grid 512 1D (XCD-swizzled), block 256 (4 waves). Wave w owns Q rows
// w*32..+31 as 2 q-subtiles of 16. KVBLK=64, K/V double-buffered;
// stage(t+1) issued before compute(t); ONE barrier per tile.
// Softmax log2-domain, defer-max THR=8, lane-partial l. P per-wave per-qb
// [16][64] hw, XOR swizzle byte^=(row&7)<<4 on write and read.
__global__ __launch_bounds__(256, 2) void flash_mfma_kernel(
    const unsigned short* __restrict__ Q, int ldq,
    const unsigned short* __restrict__ K, int ldk,
    const unsigned short* __restrict__ Vt, unsigned short* __restrict__ O)
{
    __shared__ __align__(16) unsigned short Kls[2][2 * 64 * 32]; // [buf][half d][64 kv][32 d] 8KB ea
    __shared__ __align__(16) unsigned short Vls[2][2 * 64 * 32]; // [buf][ks][64 d][32 kv]   8KB ea
    __shared__ __align__(16) unsigned short Pls[4][2][16 * 64];  // [wave][qb][16 q][64 kv] swz 16KB

    // XCD swizzle: 512 = 8 XCDs x 64; XCD c gets logical blocks [c*64,(c+1)*64)
    // = 4 consecutive bh (K/V working set < 4MB L2).
    int pbid = blockIdx.x;
    int lbid = (pbid >> 3) + (pbid & 7) * 64;
    int q0 = (lbid & 15) * 128, bh = lbid >> 4;
    int b = bh >> 4, h = bh & 15;
    int t = threadIdx.x;
    int lane = t & 63, w = t >> 6;
    int lrow = lane & 15, quad = lane >> 4;

    // Q fragments: 2 q-subtiles x 2 k-halves (A-layout: row=lrow, k=quad*8)
    bf16x8 qf[2][2];
#pragma unroll
    for (int qb = 0; qb < 2; ++qb) {
        const unsigned short* qrow =
            Q + (size_t)(b * 2048 + q0 + w * 32 + qb * 16 + lrow) * ldq + h * 64;
        qf[qb][0] = *(const bf16x8*)&qrow[quad * 8];
        qf[qb][1] = *(const bf16x8*)&qrow[32 + quad * 8];
    }

    f32x4 z = {0.f, 0.f, 0.f, 0.f};
    f32x4 acco[2][4];
    float m_run[2][4], l_run[2][4];
#pragma unroll
    for (int qb = 0; qb < 2; ++qb)
#pragma unroll
        for (int r = 0; r < 4; ++r) {
            acco[qb][r] = z;
            m_run[qb][r] = -1e30f;
            l_run[qb][r] = 0.f;   // lane-partial sum
        }

    // staging: thread t covers row t>>2 (0..63), segment (t&3)*8
    int row4 = t >> 2;
    int seg = (t & 3) * 8;
    const unsigned short* kg = K + (size_t)(b * 2048 + row4) * ldk + h * 64 + seg;
    const unsigned short* vg = Vt + (size_t)(bh * 64 + row4) * 2048 + seg;

    char* pb[2] = { (char*)&Pls[w][0][0], (char*)&Pls[w][1][0] };

    // prologue: stage tile 0 -> buf 0
    load_lds16(kg,      &Kls[0][t * 8]);
    load_lds16(kg + 32, &Kls[0][2048 + t * 8]);
    load_lds16(vg,      &Vls[0][t * 8]);
    load_lds16(vg + 32, &Vls[0][2048 + t * 8]);
    __syncthreads();

    int cur = 0;
    for (int kt = 0; kt < 2048; kt += 64) {
        // issue next-tile stage into buf cur^1; latency hides under compute
        if (kt + 64 < 2048) {
            const unsigned short* kgk = kg + (size_t)(kt + 64) * ldk;
            const unsigned short* vgk = vg + kt + 64;
            int nb = cur ^ 1;
            load_lds16(kgk,      &Kls[nb][t * 8]);
            load_lds16(kgk + 32, &Kls[nb][2048 + t * 8]);
            load_lds16(vgk,      &Vls[nb][t * 8]);
            load_lds16(vgk + 32, &Vls[nb][2048 + t * 8]);
        }

        // S = Q K^T : 32 q rows x 64 kv; K-frags shared across q-subtiles
        f32x4 s[2][4];
        __builtin_amdgcn_s_setprio(1);
#pragma unroll
        for (int kt8 = 0; kt8 < 4; ++kt8) {
            bf16x8 k0 = *(const bf16x8*)&Kls[cur][(kt8 * 16 + lrow) * 32 + quad * 8];
            bf16x8 k1 = *(const bf16x8*)&Kls[cur][2048 + (kt8 * 16 + lrow) * 32 + quad * 8];
            s[0][kt8] = mfma_bf16(qf[0][0], k0, z);
            s[0][kt8] = mfma_bf16(qf[0][1], k1, s[0][kt8]);
            s[1][kt8] = mfma_bf16(qf[1][0], k0, z);
            s[1][kt8] = mfma_bf16(qf[1][1], k1, s[1][kt8]);
        }
        __builtin_amdgcn_s_setprio(0);

        // per q-subtile: softmax (log2, defer-max) -> P (swizzled writes)
#pragma unroll
        for (int qb = 0; qb < 2; ++qb) {
            float pm[4];
#pragma unroll
            for (int r = 0; r < 4; ++r)
                pm[r] = fmaxf(fmaxf(s[qb][0][r], s[qb][1][r]),
                              fmaxf(s[qb][2][r], s[qb][3][r]));
            bool ok = (pm[0] <= m_run[qb][0] + 8.f) && (pm[1] <= m_run[qb][1] + 8.f)
                   && (pm[2] <= m_run[qb][2] + 8.f) && (pm[3] <= m_run[qb][3] + 8.f);
            if (!__all(ok)) {
                // rare path: full 16-lane max reduce + rescale
#pragma unroll
                for (int r = 0; r < 4; ++r) {
#pragma unroll
                    for (int off = 1; off < 16; off <<= 1)
                        pm[r] = fmaxf(pm[r], __shfl_xor(pm[r], off, 64));
                    float mnew = fmaxf(m_run[qb][r], pm[r]);
                    float al = exp2_fast(m_run[qb][r] - mnew);
                    m_run[qb][r] = mnew;
                    l_run[qb][r] *= al;
#pragma unroll
                    for (int nt = 0; nt < 4; ++nt) acco[qb][nt][r] *= al;
                }
            }
            // p = exp2(s - m), lane-partial l, P -> swizzled LDS (wave-local)
#pragma unroll
            for (int kt8 = 0; kt8 < 4; ++kt8)
#pragma unroll
                for (int r = 0; r < 4; ++r) {
                    float p = exp2_fast(s[qb][kt8][r] - m_run[qb][r]);
                    l_run[qb][r] += p;
                    int row = quad * 4 + r;
                    int boff = (row * 128 + (kt8 * 16 + lrow) * 2) ^ ((row & 7) << 4);
                    *(unsigned short*)(pb[qb] + boff) = f2bfu(p);
                }
        }

        // PV: V-frags shared across both q-subtiles; swizzled b128 P reads
        __builtin_amdgcn_s_setprio(1);
#pragma unroll
        for (int ks = 0; ks < 2; ++ks) {
            int rb = (lrow * 128 + ks * 64 + quad * 16) ^ ((lrow & 7) << 4);
            bf16x8 pf0 = *(const bf16x8*)(pb[0] + rb);
            bf16x8 pf1 = *(const bf16x8*)(pb[1] + rb);
#pragma unroll
            for (int nt = 0; nt < 4; ++nt) {
                bf16x8 vf = *(const bf16x8*)&Vls[cur][ks * 2048 + (nt * 16 + lrow) * 32 + quad * 8];
                acco[0][nt] = mfma_bf16(pf0, vf, acco[0][nt]);
                acco[1][nt] = mfma_bf16(pf1, vf, acco[1][nt]);
            }
        }
        __builtin_amdgcn_s_setprio(0);

        __syncthreads();   // drains vmcnt(0): next tile staged; buf[cur] free
        cur ^= 1;
    }

    // epilogue: reduce lane-partial l across the 16-lane row group, write O
#pragma unroll
    for (int qb = 0; qb < 2; ++qb)
#pragma unroll
        for (int r = 0; r < 4; ++r) {
            float lr = l_run[qb][r];
#pragma unroll
            for (int off = 1; off < 16; off <<= 1)
                lr += __shfl_xor(lr, off, 64);
            float rl = 1.0f / lr;
            int row = b * 2048 + q0 + w * 32 + qb * 16 + quad * 4 + r;
#pragma unroll
            for (int nt = 0; nt < 4; ++nt)
                O[(size_t)row * 1024 + h * 64 + nt * 16 + lrow] =
                    f2bfu(acco[qb][nt][r] * rl);
        }
}

// ---------------- launch ----------------

extern "C" void kernel_launch(void* const* d_in, const int* in_sizes, int n_in,
                              void* d_out, int out_size, void* d_ws, size_t ws_size,
                              hipStream_t stream) {
    const float* x   = (const float*)d_in[0];
    const float* Wq  = (const float*)d_in[1];
    const float* Wkv = (const float*)d_in[2];
    const float* Wk1 = (const float*)d_in[3];
    const float* Wk2 = (const float*)d_in[4];
    const float* Wv1 = (const float*)d_in[5];
    const float* Wv2 = (const float*)d_in[6];
    const float* Wo  = (const float*)d_in[7];
    const float* bo  = (const float*)d_in[8];
    float* out = (float*)d_out;

    unsigned short* p = (unsigned short*)d_ws;
    unsigned short* xb    = p; p += 4194304;   // [4096][1024]
    unsigned short* Wkvb  = p; p += 2097152;   // [1024][2048] bf16, layout kept
    unsigned short* WqkvT = p; p += 2097152;   // [2048][1024]: WqT*s | WckT | WcvT
    unsigned short* WoT   = p; p += 1048576;   // [1024][1024]
    unsigned short* Wk1T  = p; p += 524288;    // [512][1024]
    unsigned short* Wv1T  = p; p += 524288;    // [512][1024]
    unsigned short* Wk2T  = p; p += 524288;    // [1024][512]
    unsigned short* Wv2T  = p; p += 524288;    // [1024][512]
    unsigned short* qkv2  = p; p += 8388608;   // [4096][2048]  (q | k1 | v1)
    unsigned short* attnb = p; p += 4194304;   // [4096][1024]
    unsigned short* kvo   = p; p += 4194304;   // [4096][1024]  k
    unsigned short* vtb   = p; p += 4194304;   // [32*64][2048]

    dim3 blk(256);
    const float qscale = 0.125f * 1.44269504f;  // Dh^-0.5 * log2(e)

    // prep: cvt_x (4096) + cvt_Wkv (2048) + transposes (1024) = 7168 blocks
    prep_kernel<<<7168, blk, 0, stream>>>(
        x, xb, Wkv, Wkvb, Wq, Wo, Wk1, Wv1, Wk2, Wv2,
        WqkvT, WoT, Wk1T, Wv1T, Wk2T, Wv2T, qscale);

    // WckT[512][1024] = Wk1T @ Wkv_k^T ; WcvT = Wv1T @ Wkv_v^T  (z-batched)
    gemm_bf16_kernel<64><<<dim3(16, 4, 2), blk, 0, stream>>>(
        Wk1T, Wv1T, Wkvb, Wkvb + 1024,
        WqkvT + 1024 * 1024, WqkvT + 1536 * 1024,
        1024, 2048, 1024, 1024, nullptr, 0, 0);

    // [q | k1 | v1] = x @ [Wq*s | Wck | Wcv] -> qkv2 [4096][2048]; relu col>=1024
    gemm_bf16_kernel<128><<<dim3(16, 32, 1), blk, 0, stream>>>(
        xb, xb, WqkvT, WqkvT, qkv2, qkv2, 1024, 1024, 2048, 1024, nullptr, 2, 0);

    // k = k1 @ Wk2 -> kvo [4096][1024]; v = v1 @ Wv2 -> TRANSPOSED into vtb
    gemm_bf16_kernel<128, true><<<dim3(8, 32, 2), blk, 0, stream>>>(
        qkv2 + 1024, qkv2 + 1536, Wk2T, Wv2T, kvo, vtb,
        2048, 512, 1024, 512, nullptr, 0, 0);

    flash_mfma_kernel<<<dim3(512), blk, 0, stream>>>(qkv2, 2048, kvo, 1024, vtb, attnb);

    // out = attn @ Wo + bo (fp32), BN=64 for occupancy
    gemm_bf16_kernel<64><<<dim3(16, 32, 1), blk, 0, stream>>>(
        attnb, attnb, WoT, WoT, out, out, 1024, 1024, 1024, 1024, bo, 0, 1);
}